// Round 8
// baseline (328.622 us; speedup 1.0000x reference)
//
#include <hip/hip_runtime.h>
#include <stdint.h>

typedef __attribute__((ext_vector_type(4))) float f32x4;
typedef __attribute__((ext_vector_type(8))) short short8;
typedef __attribute__((ext_vector_type(2))) unsigned int u32x2;

#define MFMA16(a, b, c) __builtin_amdgcn_mfma_f32_16x16x32_bf16((a), (b), (c), 0, 0, 0)

__device__ __forceinline__ unsigned short f2bf(float f) {
  unsigned int x = __float_as_uint(f);
  return (unsigned short)((x + 0x7fffu + ((x >> 16) & 1u)) >> 16);
}

__device__ __forceinline__ unsigned int cvtpk(float lo, float hi) {
  unsigned int d;
  asm("v_cvt_pk_bf16_f32 %0, %1, %2" : "=v"(d) : "v"(lo), "v"(hi));
  return d;
}

__device__ __forceinline__ void gl2lds16(const void* g, void* l) {
  __builtin_amdgcn_global_load_lds((const __attribute__((address_space(1))) void*)g,
                                   (__attribute__((address_space(3))) void*)l, 16, 0, 0);
}

__device__ __forceinline__ void load8cv(const float* __restrict__ s, void* d) {
  const f32x4* p = (const f32x4*)s;
  f32x4 a = p[0], b = p[1];
  short8 t;
  t[0] = (short)f2bf(a[0]); t[1] = (short)f2bf(a[1]);
  t[2] = (short)f2bf(a[2]); t[3] = (short)f2bf(a[3]);
  t[4] = (short)f2bf(b[0]); t[5] = (short)f2bf(b[1]);
  t[6] = (short)f2bf(b[2]); t[7] = (short)f2bf(b[3]);
  *(short8*)d = t;
}

#define BAR_V4 asm volatile("s_waitcnt vmcnt(4)\ns_barrier" ::: "memory")
#define BAR_V10 asm volatile("s_waitcnt vmcnt(10)\ns_barrier" ::: "memory")
#define BAR_V0 asm volatile("s_waitcnt vmcnt(0)\ns_barrier" ::: "memory")
#define BAR_RAW asm volatile("s_barrier" ::: "memory")

// ---------------------------------------------------------------------------
// cast weights (4x1M) AND inputs (3x4M) f32 -> bf16 in one pass.
// ---------------------------------------------------------------------------
__global__ __launch_bounds__(256) void cast_all(const float* __restrict__ wq,
                                                const float* __restrict__ wk,
                                                const float* __restrict__ wv,
                                                const float* __restrict__ wo,
                                                const float* __restrict__ q_in,
                                                const float* __restrict__ k_in,
                                                const float* __restrict__ v_in,
                                                unsigned short* __restrict__ W16,
                                                unsigned short* __restrict__ Qin,
                                                unsigned short* __restrict__ Kin,
                                                unsigned short* __restrict__ Vin) {
  int i = blockIdx.x * 256 + threadIdx.x;  // 0..2097151 (x8 elems)
  if (i < 524288) {                        // weights: 4 x 1M elems
    int which = i >> 17;
    int off = (i & 131071) * 8;
    const float* src = which == 0 ? wq : which == 1 ? wk : which == 2 ? wv : wo;
    load8cv(src + off, W16 + (size_t)which * 1048576 + off);
  } else {                                 // inputs: 3 x 4M elems
    int j = i - 524288;
    int which = j >> 19;
    int off = (j & 524287) * 8;
    const float* src = which == 0 ? q_in : which == 1 ? k_in : v_in;
    unsigned short* dst = which == 0 ? Qin : which == 1 ? Kin : Vin;
    load8cv(src + off, dst + off);
  }
}

// ---------------------------------------------------------------------------
// Pure-bf16 QKV projection: grid.z selects {Q,K,V}. 128x64, BK=64, both
// operands via global_load_lds (o_proj structure, no VALU convert).
// ---------------------------------------------------------------------------
__global__ __launch_bounds__(256) void qkv_proj(const unsigned short* __restrict__ Qin,
                                                const unsigned short* __restrict__ Kin,
                                                const unsigned short* __restrict__ Vin,
                                                const unsigned short* __restrict__ W16,
                                                const float* __restrict__ bq,
                                                const float* __restrict__ bk,
                                                const float* __restrict__ bv,
                                                unsigned short* __restrict__ Q16,
                                                unsigned short* __restrict__ K16,
                                                unsigned short* __restrict__ V16) {
  const int z = blockIdx.z;
  const unsigned short* A = z == 0 ? Qin : z == 1 ? Kin : Vin;
  const unsigned short* Bt = W16 + (size_t)z * 1048576;
  const float* bias = z == 0 ? bq : z == 1 ? bk : bv;
  unsigned short* C = z == 0 ? Q16 : z == 1 ? K16 : V16;
  const float oscale = z == 0 ? 0.125f : 1.0f;
  const int K = 1024, N = 1024;

  __shared__ __align__(16) char lds[24576];
  char* As = lds;
  char* Bs = lds + 16384;
  const int tid = threadIdx.x;
  const int lane = tid & 63;
  const int wv = tid >> 6;
  const int g = lane >> 4, r = lane & 15;
  const int wm = wv >> 1, wn = wv & 1;
  const int m0 = blockIdx.y * 128, n0 = blockIdx.x * 64;

  f32x4 acc[4][2];
#pragma unroll
  for (int m = 0; m < 4; ++m)
#pragma unroll
    for (int n = 0; n < 2; ++n) acc[m][n] = (f32x4){0.f, 0.f, 0.f, 0.f};

  for (int k0 = 0; k0 < K; k0 += 64) {
    __syncthreads();
#pragma unroll
    for (int i = 0; i < 2; ++i) {
      int c = (wv * 2 + i) * 64 + lane;
      int row = c >> 3;
      gl2lds16(Bt + (size_t)(n0 + row) * K + k0 + (c & 7) * 8, Bs + (wv * 2 + i) * 1024);
    }
#pragma unroll
    for (int i = 0; i < 4; ++i) {
      int c = (wv * 4 + i) * 64 + lane;
      int row = c >> 3;
      gl2lds16(A + (size_t)(m0 + row) * K + k0 + (c & 7) * 8, As + (wv * 4 + i) * 1024);
    }
    __syncthreads();
#pragma unroll
    for (int kk = 0; kk < 2; ++kk) {
      short8 af[4], bfr[2];
#pragma unroll
      for (int m = 0; m < 4; ++m)
        af[m] = *(const short8*)(As + (wm * 64 + m * 16 + r) * 128 + kk * 64 + g * 16);
#pragma unroll
      for (int n = 0; n < 2; ++n)
        bfr[n] = *(const short8*)(Bs + (wn * 32 + n * 16 + r) * 128 + kk * 64 + g * 16);
#pragma unroll
      for (int m = 0; m < 4; ++m)
#pragma unroll
        for (int n = 0; n < 2; ++n) acc[m][n] = MFMA16(af[m], bfr[n], acc[m][n]);
    }
  }

#pragma unroll
  for (int n = 0; n < 2; ++n) {
    int col = n0 + wn * 32 + n * 16 + r;
    float bv_ = bias[col];
#pragma unroll
    for (int m = 0; m < 4; ++m)
#pragma unroll
      for (int i = 0; i < 4; ++i) {
        int rowg = m0 + wm * 64 + m * 16 + 4 * g + i;
        C[(size_t)rowg * N + col] = f2bf((acc[m][n][i] + bv_) * oscale);
      }
  }
}

// ---------------------------------------------------------------------------
// O-projection (unchanged round-7): bf16 A via global_load_lds, f32 out.
// ---------------------------------------------------------------------------
__global__ __launch_bounds__(256) void o_proj(const unsigned short* __restrict__ A,
                                              const unsigned short* __restrict__ Bt,
                                              const float* __restrict__ bias,
                                              float* __restrict__ C) {
  const int K = 1024, N = 1024;
  __shared__ __align__(16) char lds[24576];
  char* As = lds;
  char* Bs = lds + 16384;
  const int tid = threadIdx.x;
  const int lane = tid & 63;
  const int wv = tid >> 6;
  const int g = lane >> 4, r = lane & 15;
  const int wm = wv >> 1, wn = wv & 1;
  const int m0 = blockIdx.y * 128, n0 = blockIdx.x * 64;

  f32x4 acc[4][2];
#pragma unroll
  for (int m = 0; m < 4; ++m)
#pragma unroll
    for (int n = 0; n < 2; ++n) acc[m][n] = (f32x4){0.f, 0.f, 0.f, 0.f};

  for (int k0 = 0; k0 < K; k0 += 64) {
    __syncthreads();
#pragma unroll
    for (int i = 0; i < 2; ++i) {
      int c = (wv * 2 + i) * 64 + lane;
      int row = c >> 3;
      gl2lds16(Bt + (size_t)(n0 + row) * K + k0 + (c & 7) * 8, Bs + (wv * 2 + i) * 1024);
    }
#pragma unroll
    for (int i = 0; i < 4; ++i) {
      int c = (wv * 4 + i) * 64 + lane;
      int row = c >> 3;
      gl2lds16(A + (size_t)(m0 + row) * K + k0 + (c & 7) * 8, As + (wv * 4 + i) * 1024);
    }
    __syncthreads();
#pragma unroll
    for (int kk = 0; kk < 2; ++kk) {
      short8 af[4], bfr[2];
#pragma unroll
      for (int m = 0; m < 4; ++m)
        af[m] = *(const short8*)(As + (wm * 64 + m * 16 + r) * 128 + kk * 64 + g * 16);
#pragma unroll
      for (int n = 0; n < 2; ++n)
        bfr[n] = *(const short8*)(Bs + (wn * 32 + n * 16 + r) * 128 + kk * 64 + g * 16);
#pragma unroll
      for (int m = 0; m < 4; ++m)
#pragma unroll
        for (int n = 0; n < 2; ++n) acc[m][n] = MFMA16(af[m], bfr[n], acc[m][n]);
    }
  }

#pragma unroll
  for (int n = 0; n < 2; ++n) {
    int col = n0 + wn * 32 + n * 16 + r;
    float bv_ = bias[col];
#pragma unroll
    for (int m = 0; m < 4; ++m)
#pragma unroll
      for (int i = 0; i < 4; ++i) {
        int rowg = m0 + wm * 64 + m * 16 + 4 * g + i;
        C[(size_t)rowg * N + col] = acc[m][n][i] + bv_;
      }
  }
}

// ---------------------------------------------------------------------------
__global__ __launch_bounds__(256) void transpose_v(const unsigned short* __restrict__ V,
                                                   unsigned short* __restrict__ Vt) {
  int t = blockIdx.x * 256 + threadIdx.x;
  int d = t & 63;
  int sc = (t >> 6) & 255;
  int bh = t >> 14;
  int b = bh >> 4, h = bh & 15;
  unsigned short vals[8];
#pragma unroll
  for (int j = 0; j < 8; ++j)
    vals[j] = V[(size_t)(b * 2048 + sc * 8 + j) * 1024 + h * 64 + d];
  *(short8*)&Vt[((size_t)bh * 64 + d) * 2048 + sc * 8] = *(short8*)vals;
}

// ---------------------------------------------------------------------------
// Fused attention v8 = round-7 + V direct-to-register (no V staging).
// Pass 2 per tile: [issue V-reg loads (8)] [stage K t+1 (2 gl2lds)]
// [BAR vmcnt(10): guarantees stage-t retired (in-order), keeps V+next-stage
// in flight] [QK^T + exp + direct store + cvt_pk P] [setprio PV] [BAR_RAW].
// LDS: pass1 dbuf 2x16KB (KVBLK=128 K); pass2 uses 8KB of each; pbuf 8KB.
// ---------------------------------------------------------------------------
__global__ __launch_bounds__(256, 4) void attn_fused(const unsigned short* __restrict__ Q,
                                                     const unsigned short* __restrict__ K,
                                                     const unsigned short* __restrict__ Vt,
                                                     float* __restrict__ attn,
                                                     unsigned short* __restrict__ O) {
  __shared__ __align__(16) char lds[40960];
  const int tid = threadIdx.x;
  const int lane = tid & 63;
  const int wv = tid >> 6;
  const int g = lane >> 4, r = lane & 15;
  int nb = (blockIdx.x & 7) * 128 + (blockIdx.x >> 3);
  const int qt = nb & 31, bh = nb >> 5, h = bh & 15, b = bh >> 4;
  const int qloc = qt * 64 + wv * 16;
  const int qrow0 = b * 2048 + qloc;
  const unsigned short* Kbh = K + (size_t)b * 2048 * 1024 + h * 64;
  const unsigned short* Vbh = Vt + (size_t)bh * 64 * 2048;
  float* attn_bh = attn + (size_t)bh * 2048 * 2048;
  char* pb = lds + 32768 + wv * 2048;
  const int swr = (r & 7) << 4;

  short8 qf[2];
#pragma unroll
  for (int kk = 0; kk < 2; ++kk)
    qf[kk] = *(const short8*)&Q[(size_t)(qrow0 + r) * 1024 + h * 64 + kk * 32 + g * 8];

#define P1_ISSUE(bb, ktt)                                                      \
  do {                                                                         \
    _Pragma("unroll") for (int i_ = 0; i_ < 4; ++i_) {                         \
      int c_ = (wv * 4 + i_) * 64 + lane;                                      \
      int kr_ = c_ >> 3;                                                       \
      int scb_ = ((c_ & 7) * 16) ^ ((kr_ & 7) << 4);                           \
      gl2lds16(Kbh + (size_t)((ktt) + kr_) * 1024 + (scb_ >> 1),               \
               (bb) + (wv * 4 + i_) * 1024);                                   \
    }                                                                          \
  } while (0)
#define P2_ISSUE(bb, ktt)                                                      \
  do {                                                                         \
    _Pragma("unroll") for (int i_ = 0; i_ < 2; ++i_) {                         \
      int c_ = (wv * 2 + i_) * 64 + lane;                                      \
      int kr_ = c_ >> 3;                                                       \
      int scb_ = ((c_ & 7) * 16) ^ ((kr_ & 7) << 4);                           \
      gl2lds16(Kbh + (size_t)((ktt) + kr_) * 1024 + (scb_ >> 1),               \
               (bb) + (wv * 2 + i_) * 1024);                                   \
    }                                                                          \
  } while (0)

  // ---------------- pass 1: per-lane exp-sum, KVBLK=128 (K-only LDS) -------
  float lrow = 0.f;
  int cur = 0;
  P1_ISSUE(lds, 0);
  for (int t = 0; t < 16; ++t) {
    char* bcur = lds + (cur << 14);
    char* bnxt = lds + ((cur ^ 1) << 14);
    if (t < 15) {
      P1_ISSUE(bnxt, (t + 1) * 128);
      BAR_V4;
    } else {
      BAR_V0;
    }
#pragma unroll
    for (int ct = 0; ct < 8; ++ct) {
      int row = ct * 16 + r;
      int sw = (row & 7) << 4;
      short8 kf0 = *(const short8*)(bcur + ((row * 128 + g * 16) ^ sw));
      short8 kf1 = *(const short8*)(bcur + ((row * 128 + 64 + g * 16) ^ sw));
      f32x4 s = (f32x4){0.f, 0.f, 0.f, 0.f};
      s = MFMA16(kf0, qf[0], s);
      s = MFMA16(kf1, qf[1], s);
      lrow += (__expf(s[0]) + __expf(s[1])) + (__expf(s[2]) + __expf(s[3]));
    }
    BAR_RAW;
    cur ^= 1;
  }
  lrow += __shfl_xor(lrow, 16);
  lrow += __shfl_xor(lrow, 32);
  const float negml = -__logf(lrow);
  const f32x4 cinit = (f32x4){negml, negml, negml, negml};

  // ---------------- pass 2: V-in-reg, direct store + PV, KVBLK=64 ----------
  f32x4 oacc[4];
#pragma unroll
  for (int i = 0; i < 4; ++i) oacc[i] = (f32x4){0.f, 0.f, 0.f, 0.f};

  float* arow = attn_bh + (size_t)(qloc + r) * 2048 + 4 * g;
  const unsigned short* Vlane = Vbh + (size_t)r * 2048 + g * 8;
  cur = 0;
  P2_ISSUE(lds, 0);
  for (int t = 0; t < 32; ++t) {
    char* bcur = lds + (cur << 14);
    char* bnxt = lds + ((cur ^ 1) << 14);
    int kt = t * 64;
    // V fragments for THIS tile straight from L2 (issued first, consumed in PV)
    short8 vreg[2][4];
#pragma unroll
    for (int kk2 = 0; kk2 < 2; ++kk2)
#pragma unroll
      for (int c2 = 0; c2 < 4; ++c2)
        vreg[kk2][c2] = *(const short8*)(Vlane + (size_t)(c2 * 16) * 2048 + kt + kk2 * 32);
    if (t < 31) P2_ISSUE(bnxt, kt + 64);
    BAR_V10;  // stage-t retired (in-order); V + next-stage stay in flight
    // QK^T (C-init = -ln l) -> p = expf(s) already normalized
#pragma unroll
    for (int ct = 0; ct < 4; ++ct) {
      int row = ct * 16 + r;
      int sw = (row & 7) << 4;
      short8 kf0 = *(const short8*)(bcur + ((row * 128 + g * 16) ^ sw));
      short8 kf1 = *(const short8*)(bcur + ((row * 128 + 64 + g * 16) ^ sw));
      f32x4 s = MFMA16(kf0, qf[0], cinit);
      s = MFMA16(kf1, qf[1], s);
      f32x4 p;
      p[0] = __expf(s[0]); p[1] = __expf(s[1]);
      p[2] = __expf(s[2]); p[3] = __expf(s[3]);
      *(f32x4*)(arow + kt + 16 * ct) = p;
      u32x2 pk;
      pk[0] = cvtpk(p[0], p[1]);
      pk[1] = cvtpk(p[2], p[3]);
      *(u32x2*)(pb + ((r * 128 + (ct * 16 + 4 * g) * 2) ^ swr)) = pk;
    }
    // PV cluster (register V)
    __builtin_amdgcn_s_setprio(1);
#pragma unroll
    for (int kk2 = 0; kk2 < 2; ++kk2) {
      short8 pa = *(const short8*)(pb + ((r * 128 + kk2 * 64 + g * 16) ^ swr));
#pragma unroll
      for (int ct2 = 0; ct2 < 4; ++ct2)
        oacc[ct2] = MFMA16(pa, vreg[kk2][ct2], oacc[ct2]);
    }
    __builtin_amdgcn_s_setprio(0);
    BAR_RAW;
    cur ^= 1;
  }
#pragma unroll
  for (int ct2 = 0; ct2 < 4; ++ct2)
#pragma unroll
    for (int i = 0; i < 4; ++i)
      O[(size_t)(qrow0 + 4 * g + i) * 1024 + h * 64 + ct2 * 16 + r] = f2bf(oacc[ct2][i]);
#undef P1_ISSUE
#undef P2_ISSUE
}

// ---------------------------------------------------------------------------
extern "C" void kernel_launch(void* const* d_in, const int* in_sizes, int n_in,
                              void* d_out, int out_size, void* d_ws, size_t ws_size,
                              hipStream_t stream) {
  const float* q_in = (const float*)d_in[0];
  const float* k_in = (const float*)d_in[1];
  const float* v_in = (const float*)d_in[2];
  const float* wq = (const float*)d_in[3];
  const float* bq = (const float*)d_in[4];
  const float* wk = (const float*)d_in[5];
  const float* bk = (const float*)d_in[6];
  const float* wv = (const float*)d_in[7];
  const float* bv = (const float*)d_in[8];
  const float* wo = (const float*)d_in[9];
  const float* bo = (const float*)d_in[10];

  char* ws = (char*)d_ws;
  const size_t MB8 = 8ull * 1024 * 1024;
  unsigned short* W16  = (unsigned short*)(ws);
  unsigned short* Qin  = (unsigned short*)(ws + MB8);
  unsigned short* Kin  = (unsigned short*)(ws + 2 * MB8);
  unsigned short* Vin  = (unsigned short*)(ws + 3 * MB8);
  unsigned short* Q16  = (unsigned short*)(ws + 4 * MB8);
  unsigned short* K16  = (unsigned short*)(ws + 5 * MB8);
  unsigned short* V16  = (unsigned short*)(ws + 6 * MB8);
  unsigned short* Vt   = (unsigned short*)(ws + 7 * MB8);
  unsigned short* O16  = (unsigned short*)(ws + 8 * MB8);

  float* out = (float*)d_out;
  float* attn = out + 4194304ull;

  dim3 blk(256);
  cast_all<<<dim3(8192), blk, 0, stream>>>(wq, wk, wv, wo, q_in, k_in, v_in, W16, Qin, Kin, Vin);
  qkv_proj<<<dim3(16, 32, 3), blk, 0, stream>>>(Qin, Kin, Vin, W16, bq, bk, bv, Q16, K16, V16);
  transpose_v<<<dim3(2048), blk, 0, stream>>>(V16, Vt);
  attn_fused<<<dim3(1024), blk, 0, stream>>>(Q16, K16, Vt, attn, O16);
  o_proj<<<dim3(16, 32), blk, 0, stream>>>(O16, W16 + 3145728, bo, out);
}

// Round 9
// 307.121 us; speedup vs baseline: 1.0700x; 1.0700x over previous
//
#include <hip/hip_runtime.h>
#include <stdint.h>

typedef __attribute__((ext_vector_type(4))) float f32x4;
typedef __attribute__((ext_vector_type(8))) short short8;
typedef __attribute__((ext_vector_type(2))) unsigned int u32x2;

#define MFMA16(a, b, c) __builtin_amdgcn_mfma_f32_16x16x32_bf16((a), (b), (c), 0, 0, 0)

__device__ __forceinline__ unsigned short f2bf(float f) {
  unsigned int x = __float_as_uint(f);
  return (unsigned short)((x + 0x7fffu + ((x >> 16) & 1u)) >> 16);
}

__device__ __forceinline__ unsigned int cvtpk(float lo, float hi) {
  unsigned int d;
  asm("v_cvt_pk_bf16_f32 %0, %1, %2" : "=v"(d) : "v"(lo), "v"(hi));
  return d;
}

__device__ __forceinline__ void gl2lds16(const void* g, void* l) {
  __builtin_amdgcn_global_load_lds((const __attribute__((address_space(1))) void*)g,
                                   (__attribute__((address_space(3))) void*)l, 16, 0, 0);
}

__device__ __forceinline__ void load8cv(const float* __restrict__ s, void* d) {
  const f32x4* p = (const f32x4*)s;
  f32x4 a = p[0], b = p[1];
  short8 t;
  t[0] = (short)f2bf(a[0]); t[1] = (short)f2bf(a[1]);
  t[2] = (short)f2bf(a[2]); t[3] = (short)f2bf(a[3]);
  t[4] = (short)f2bf(b[0]); t[5] = (short)f2bf(b[1]);
  t[6] = (short)f2bf(b[2]); t[7] = (short)f2bf(b[3]);
  *(short8*)d = t;
}

#define BAR_V4 asm volatile("s_waitcnt vmcnt(4)\ns_barrier" ::: "memory")
#define BAR_V0 asm volatile("s_waitcnt vmcnt(0)\ns_barrier" ::: "memory")
#define BAR_RAW asm volatile("s_barrier" ::: "memory")

// ---------------------------------------------------------------------------
__global__ __launch_bounds__(256) void cast_weights(const float* __restrict__ wq,
                                                    const float* __restrict__ wk,
                                                    const float* __restrict__ wv,
                                                    const float* __restrict__ wo,
                                                    unsigned short* __restrict__ dst) {
  int i = blockIdx.x * 256 + threadIdx.x;
  int which = i >> 17;
  int off = (i & 131071) * 8;
  const float* src = which == 0 ? wq : which == 1 ? wk : which == 2 ? wv : wo;
  load8cv(src + off, dst + (size_t)which * 1048576 + off);
}

// ---------------------------------------------------------------------------
// QKV projection (round-7 form): f32 A reg-staged w/ convert; bf16 W via
// global_load_lds. 128x64 tile, BK=64, 4 waves.
// ---------------------------------------------------------------------------
__global__ __launch_bounds__(256) void qkv_proj(const float* __restrict__ q_in,
                                                const float* __restrict__ k_in,
                                                const float* __restrict__ v_in,
                                                const unsigned short* __restrict__ W16,
                                                const float* __restrict__ bq,
                                                const float* __restrict__ bk,
                                                const float* __restrict__ bv,
                                                unsigned short* __restrict__ Q16,
                                                unsigned short* __restrict__ K16,
                                                unsigned short* __restrict__ V16) {
  const int z = blockIdx.z;
  const float* A = z == 0 ? q_in : z == 1 ? k_in : v_in;
  const unsigned short* Bt = W16 + (size_t)z * 1048576;
  const float* bias = z == 0 ? bq : z == 1 ? bk : bv;
  unsigned short* C = z == 0 ? Q16 : z == 1 ? K16 : V16;
  const float oscale = z == 0 ? 0.125f : 1.0f;
  const int K = 1024, N = 1024;

  __shared__ __align__(16) char lds[24576];
  char* As = lds;
  char* Bs = lds + 16384;
  const int tid = threadIdx.x;
  const int lane = tid & 63;
  const int wv = tid >> 6;
  const int g = lane >> 4, r = lane & 15;
  const int wm = wv >> 1, wn = wv & 1;
  const int m0 = blockIdx.y * 128, n0 = blockIdx.x * 64;

  f32x4 acc[4][2];
#pragma unroll
  for (int m = 0; m < 4; ++m)
#pragma unroll
    for (int n = 0; n < 2; ++n) acc[m][n] = (f32x4){0.f, 0.f, 0.f, 0.f};

  for (int k0 = 0; k0 < K; k0 += 64) {
    __syncthreads();
#pragma unroll
    for (int i = 0; i < 2; ++i) {
      int c = (wv * 2 + i) * 64 + lane;
      int row = c >> 3;
      gl2lds16(Bt + (size_t)(n0 + row) * K + k0 + (c & 7) * 8, Bs + (wv * 2 + i) * 1024);
    }
#pragma unroll
    for (int i = 0; i < 4; ++i) {
      int c = tid + i * 256;
      int row = c >> 3, e = (c & 7) * 8;
      load8cv(A + (size_t)(m0 + row) * K + k0 + e, As + c * 16);
    }
    __syncthreads();
#pragma unroll
    for (int kk = 0; kk < 2; ++kk) {
      short8 af[4], bfr[2];
#pragma unroll
      for (int m = 0; m < 4; ++m)
        af[m] = *(const short8*)(As + (wm * 64 + m * 16 + r) * 128 + kk * 64 + g * 16);
#pragma unroll
      for (int n = 0; n < 2; ++n)
        bfr[n] = *(const short8*)(Bs + (wn * 32 + n * 16 + r) * 128 + kk * 64 + g * 16);
#pragma unroll
      for (int m = 0; m < 4; ++m)
#pragma unroll
        for (int n = 0; n < 2; ++n) acc[m][n] = MFMA16(af[m], bfr[n], acc[m][n]);
    }
  }

#pragma unroll
  for (int n = 0; n < 2; ++n) {
    int col = n0 + wn * 32 + n * 16 + r;
    float bv_ = bias[col];
#pragma unroll
    for (int m = 0; m < 4; ++m)
#pragma unroll
      for (int i = 0; i < 4; ++i) {
        int rowg = m0 + wm * 64 + m * 16 + 4 * g + i;
        C[(size_t)rowg * N + col] = f2bf((acc[m][n][i] + bv_) * oscale);
      }
  }
}

// ---------------------------------------------------------------------------
__global__ __launch_bounds__(256) void o_proj(const unsigned short* __restrict__ A,
                                              const unsigned short* __restrict__ Bt,
                                              const float* __restrict__ bias,
                                              float* __restrict__ C) {
  const int K = 1024, N = 1024;
  __shared__ __align__(16) char lds[24576];
  char* As = lds;
  char* Bs = lds + 16384;
  const int tid = threadIdx.x;
  const int lane = tid & 63;
  const int wv = tid >> 6;
  const int g = lane >> 4, r = lane & 15;
  const int wm = wv >> 1, wn = wv & 1;
  const int m0 = blockIdx.y * 128, n0 = blockIdx.x * 64;

  f32x4 acc[4][2];
#pragma unroll
  for (int m = 0; m < 4; ++m)
#pragma unroll
    for (int n = 0; n < 2; ++n) acc[m][n] = (f32x4){0.f, 0.f, 0.f, 0.f};

  for (int k0 = 0; k0 < K; k0 += 64) {
    __syncthreads();
#pragma unroll
    for (int i = 0; i < 2; ++i) {
      int c = (wv * 2 + i) * 64 + lane;
      int row = c >> 3;
      gl2lds16(Bt + (size_t)(n0 + row) * K + k0 + (c & 7) * 8, Bs + (wv * 2 + i) * 1024);
    }
#pragma unroll
    for (int i = 0; i < 4; ++i) {
      int c = (wv * 4 + i) * 64 + lane;
      int row = c >> 3;
      gl2lds16(A + (size_t)(m0 + row) * K + k0 + (c & 7) * 8, As + (wv * 4 + i) * 1024);
    }
    __syncthreads();
#pragma unroll
    for (int kk = 0; kk < 2; ++kk) {
      short8 af[4], bfr[2];
#pragma unroll
      for (int m = 0; m < 4; ++m)
        af[m] = *(const short8*)(As + (wm * 64 + m * 16 + r) * 128 + kk * 64 + g * 16);
#pragma unroll
      for (int n = 0; n < 2; ++n)
        bfr[n] = *(const short8*)(Bs + (wn * 32 + n * 16 + r) * 128 + kk * 64 + g * 16);
#pragma unroll
      for (int m = 0; m < 4; ++m)
#pragma unroll
        for (int n = 0; n < 2; ++n) acc[m][n] = MFMA16(af[m], bfr[n], acc[m][n]);
    }
  }

#pragma unroll
  for (int n = 0; n < 2; ++n) {
    int col = n0 + wn * 32 + n * 16 + r;
    float bv_ = bias[col];
#pragma unroll
    for (int m = 0; m < 4; ++m)
#pragma unroll
      for (int i = 0; i < 4; ++i) {
        int rowg = m0 + wm * 64 + m * 16 + 4 * g + i;
        C[(size_t)rowg * N + col] = acc[m][n][i] + bv_;
      }
  }
}

// ---------------------------------------------------------------------------
__global__ __launch_bounds__(256) void transpose_v(const unsigned short* __restrict__ V,
                                                   unsigned short* __restrict__ Vt) {
  int t = blockIdx.x * 256 + threadIdx.x;
  int d = t & 63;
  int sc = (t >> 6) & 255;
  int bh = t >> 14;
  int b = bh >> 4, h = bh & 15;
  unsigned short vals[8];
#pragma unroll
  for (int j = 0; j < 8; ++j)
    vals[j] = V[(size_t)(b * 2048 + sc * 8 + j) * 1024 + h * 64 + d];
  *(short8*)&Vt[((size_t)bh * 64 + d) * 2048 + sc * 8] = *(short8*)vals;
}

// ---------------------------------------------------------------------------
// Fused attention v9 = round-7 structure + NONTEMPORAL attention stores
// (keep K/Vt L2-resident; stop the 536MB stream from thrashing L2) +
// setprio around the PV MFMA cluster (T5, catalog attn-positive).
// ---------------------------------------------------------------------------
__global__ __launch_bounds__(256, 4) void attn_fused(const unsigned short* __restrict__ Q,
                                                     const unsigned short* __restrict__ K,
                                                     const unsigned short* __restrict__ Vt,
                                                     float* __restrict__ attn,
                                                     unsigned short* __restrict__ O) {
  __shared__ __align__(16) char lds[40960];  // dbuf 2x16KB | pbuf 4x2KB
  const int tid = threadIdx.x;
  const int lane = tid & 63;
  const int wv = tid >> 6;
  const int g = lane >> 4, r = lane & 15;
  int nb = (blockIdx.x & 7) * 128 + (blockIdx.x >> 3);
  const int qt = nb & 31, bh = nb >> 5, h = bh & 15, b = bh >> 4;
  const int qloc = qt * 64 + wv * 16;
  const int qrow0 = b * 2048 + qloc;
  const unsigned short* Kbh = K + (size_t)b * 2048 * 1024 + h * 64;
  const unsigned short* Vbh = Vt + (size_t)bh * 64 * 2048;
  float* attn_bh = attn + (size_t)bh * 2048 * 2048;
  char* pb = lds + 32768 + wv * 2048;
  const int swr = (r & 7) << 4;

  short8 qf[2];
#pragma unroll
  for (int kk = 0; kk < 2; ++kk)
    qf[kk] = *(const short8*)&Q[(size_t)(qrow0 + r) * 1024 + h * 64 + kk * 32 + g * 8];

#define P1_ISSUE(bb, ktt)                                                      \
  do {                                                                         \
    _Pragma("unroll") for (int i_ = 0; i_ < 4; ++i_) {                         \
      int c_ = (wv * 4 + i_) * 64 + lane;                                      \
      int kr_ = c_ >> 3;                                                       \
      int scb_ = ((c_ & 7) * 16) ^ ((kr_ & 7) << 4);                           \
      gl2lds16(Kbh + (size_t)((ktt) + kr_) * 1024 + (scb_ >> 1),               \
               (bb) + (wv * 4 + i_) * 1024);                                   \
    }                                                                          \
  } while (0)
#define P2_ISSUE(bb, ktt)                                                      \
  do {                                                                         \
    _Pragma("unroll") for (int i_ = 0; i_ < 4; ++i_) {                         \
      int c_ = (wv * 4 + i_) * 64 + lane;                                      \
      int kr_ = (c_ >> 3) & 63;                                                \
      int scb_ = ((c_ & 7) * 16) ^ ((kr_ & 7) << 4);                           \
      const unsigned short* src_ =                                             \
          (c_ < 512) ? (Kbh + (size_t)((ktt) + kr_) * 1024 + (scb_ >> 1))      \
                     : (Vbh + (size_t)kr_ * 2048 + (ktt) + (scb_ >> 1));       \
      gl2lds16(src_, (bb) + (wv * 4 + i_) * 1024);                             \
    }                                                                          \
  } while (0)

  // ---------------- pass 1: per-lane exp-sum (swapped layout), KVBLK=128 ----
  float lrow = 0.f;
  int cur = 0;
  P1_ISSUE(lds, 0);
  for (int t = 0; t < 16; ++t) {
    char* bcur = lds + (cur << 14);
    char* bnxt = lds + ((cur ^ 1) << 14);
    if (t < 15) {
      P1_ISSUE(bnxt, (t + 1) * 128);
      BAR_V4;
    } else {
      BAR_V0;
    }
#pragma unroll
    for (int ct = 0; ct < 8; ++ct) {
      int row = ct * 16 + r;
      int sw = (row & 7) << 4;
      short8 kf0 = *(const short8*)(bcur + ((row * 128 + g * 16) ^ sw));
      short8 kf1 = *(const short8*)(bcur + ((row * 128 + 64 + g * 16) ^ sw));
      f32x4 s = (f32x4){0.f, 0.f, 0.f, 0.f};
      s = MFMA16(kf0, qf[0], s);
      s = MFMA16(kf1, qf[1], s);
      lrow += (__expf(s[0]) + __expf(s[1])) + (__expf(s[2]) + __expf(s[3]));
    }
    BAR_RAW;
    cur ^= 1;
  }
  lrow += __shfl_xor(lrow, 16);
  lrow += __shfl_xor(lrow, 32);
  const float negml = -__logf(lrow);
  const f32x4 cinit = (f32x4){negml, negml, negml, negml};

  // ---------------- pass 2: direct nt-store + PV, KVBLK=64 ------------------
  f32x4 oacc[4];
#pragma unroll
  for (int i = 0; i < 4; ++i) oacc[i] = (f32x4){0.f, 0.f, 0.f, 0.f};

  float* arow = attn_bh + (size_t)(qloc + r) * 2048 + 4 * g;
  cur = 0;
  P2_ISSUE(lds, 0);
  for (int t = 0; t < 32; ++t) {
    char* bcur = lds + (cur << 14);
    char* bnxt = lds + ((cur ^ 1) << 14);
    int kt = t * 64;
    if (t < 31) {
      P2_ISSUE(bnxt, kt + 64);
      BAR_V4;
    } else {
      BAR_V0;
    }
    // QK^T (C-init = -ln l) -> p = expf(s) already normalized
#pragma unroll
    for (int ct = 0; ct < 4; ++ct) {
      int row = ct * 16 + r;
      int sw = (row & 7) << 4;
      short8 kf0 = *(const short8*)(bcur + ((row * 128 + g * 16) ^ sw));
      short8 kf1 = *(const short8*)(bcur + ((row * 128 + 64 + g * 16) ^ sw));
      f32x4 s = MFMA16(kf0, qf[0], cinit);
      s = MFMA16(kf1, qf[1], s);
      f32x4 p;
      p[0] = __expf(s[0]); p[1] = __expf(s[1]);
      p[2] = __expf(s[2]); p[3] = __expf(s[3]);
      // nontemporal: bypass L2 allocation for the 536MB attn stream
      __builtin_nontemporal_store(p, (f32x4*)(arow + kt + 16 * ct));
      u32x2 pk;
      pk[0] = cvtpk(p[0], p[1]);
      pk[1] = cvtpk(p[2], p[3]);
      *(u32x2*)(pb + ((r * 128 + (ct * 16 + 4 * g) * 2) ^ swr)) = pk;
    }
    // PV cluster
    __builtin_amdgcn_s_setprio(1);
#pragma unroll
    for (int kk2 = 0; kk2 < 2; ++kk2) {
      short8 pa = *(const short8*)(pb + ((r * 128 + kk2 * 64 + g * 16) ^ swr));
#pragma unroll
      for (int ct2 = 0; ct2 < 4; ++ct2) {
        int vrow = ct2 * 16 + r;
        short8 vf = *(const short8*)(bcur + 8192 +
                                     ((vrow * 128 + kk2 * 64 + g * 16) ^ ((vrow & 7) << 4)));
        oacc[ct2] = MFMA16(pa, vf, oacc[ct2]);
      }
    }
    __builtin_amdgcn_s_setprio(0);
    BAR_RAW;
    cur ^= 1;
  }
#pragma unroll
  for (int ct2 = 0; ct2 < 4; ++ct2)
#pragma unroll
    for (int i = 0; i < 4; ++i)
      O[(size_t)(qrow0 + 4 * g + i) * 1024 + h * 64 + ct2 * 16 + r] = f2bf(oacc[ct2][i]);
#undef P1_ISSUE
#undef P2_ISSUE
}

// ---------------------------------------------------------------------------
extern "C" void kernel_launch(void* const* d_in, const int* in_sizes, int n_in,
                              void* d_out, int out_size, void* d_ws, size_t ws_size,
                              hipStream_t stream) {
  const float* q_in = (const float*)d_in[0];
  const float* k_in = (const float*)d_in[1];
  const float* v_in = (const float*)d_in[2];
  const float* wq = (const float*)d_in[3];
  const float* bq = (const float*)d_in[4];
  const float* wk = (const float*)d_in[5];
  const float* bk = (const float*)d_in[6];
  const float* wv = (const float*)d_in[7];
  const float* bv = (const float*)d_in[8];
  const float* wo = (const float*)d_in[9];
  const float* bo = (const float*)d_in[10];

  char* ws = (char*)d_ws;
  const size_t MB8 = 8ull * 1024 * 1024;
  unsigned short* W16 = (unsigned short*)(ws);
  unsigned short* Q16 = (unsigned short*)(ws + MB8);
  unsigned short* K16 = (unsigned short*)(ws + 2 * MB8);
  unsigned short* V16 = (unsigned short*)(ws + 3 * MB8);
  unsigned short* Vt  = (unsigned short*)(ws + 4 * MB8);
  unsigned short* O16 = (unsigned short*)(ws + 3 * MB8);  // alias V16 (dead after transpose)

  float* out = (float*)d_out;
  float* attn = out + 4194304ull;

  dim3 blk(256);
  cast_weights<<<dim3(2048), blk, 0, stream>>>(wq, wk, wv, wo, W16);
  qkv_proj<<<dim3(16, 32, 3), blk, 0, stream>>>(q_in, k_in, v_in, W16, bq, bk, bv, Q16, K16, V16);
  transpose_v<<<dim3(2048), blk, 0, stream>>>(V16, Vt);
  attn_fused<<<dim3(1024), blk, 0, stream>>>(Q16, K16, Vt, attn, O16);
  o_proj<<<dim3(16, 32), blk, 0, stream>>>(O16, W16 + 3145728, bo, out);
}

// Round 11
// 296.551 us; speedup vs baseline: 1.1081x; 1.0356x over previous
//
#include <hip/hip_runtime.h>
#include <stdint.h>

typedef __attribute__((ext_vector_type(4))) float f32x4;
typedef __attribute__((ext_vector_type(8))) short short8;
typedef __attribute__((ext_vector_type(2))) unsigned int u32x2;

#define MFMA16(a, b, c) __builtin_amdgcn_mfma_f32_16x16x32_bf16((a), (b), (c), 0, 0, 0)
#define EXP2(x) __builtin_amdgcn_exp2f(x)   // v_exp_f32: 2^x native
#define LOG2(x) __builtin_amdgcn_logf(x)    // v_log_f32: log2 native

__device__ __forceinline__ unsigned short f2bf(float f) {
  unsigned int x = __float_as_uint(f);
  return (unsigned short)((x + 0x7fffu + ((x >> 16) & 1u)) >> 16);
}

__device__ __forceinline__ unsigned int cvtpk(float lo, float hi) {
  unsigned int d;
  asm("v_cvt_pk_bf16_f32 %0, %1, %2" : "=v"(d) : "v"(lo), "v"(hi));
  return d;
}

__device__ __forceinline__ void gl2lds16(const void* g, void* l) {
  __builtin_amdgcn_global_load_lds((const __attribute__((address_space(1))) void*)g,
                                   (__attribute__((address_space(3))) void*)l, 16, 0, 0);
}

__device__ __forceinline__ void load8cv(const float* __restrict__ s, void* d) {
  const f32x4* p = (const f32x4*)s;
  f32x4 a = p[0], b = p[1];
  short8 t;
  t[0] = (short)f2bf(a[0]); t[1] = (short)f2bf(a[1]);
  t[2] = (short)f2bf(a[2]); t[3] = (short)f2bf(a[3]);
  t[4] = (short)f2bf(b[0]); t[5] = (short)f2bf(b[1]);
  t[6] = (short)f2bf(b[2]); t[7] = (short)f2bf(b[3]);
  *(short8*)d = t;
}

#define BAR_V4 asm volatile("s_waitcnt vmcnt(4)\ns_barrier" ::: "memory")
#define BAR_V0 asm volatile("s_waitcnt vmcnt(0)\ns_barrier" ::: "memory")
#define BAR_RAW asm volatile("s_barrier" ::: "memory")

// ---------------------------------------------------------------------------
__global__ __launch_bounds__(256) void cast_weights(const float* __restrict__ wq,
                                                    const float* __restrict__ wk,
                                                    const float* __restrict__ wv,
                                                    const float* __restrict__ wo,
                                                    unsigned short* __restrict__ dst) {
  int i = blockIdx.x * 256 + threadIdx.x;
  int which = i >> 17;
  int off = (i & 131071) * 8;
  const float* src = which == 0 ? wq : which == 1 ? wk : which == 2 ? wv : wo;
  load8cv(src + off, dst + (size_t)which * 1048576 + off);
}

// ---------------------------------------------------------------------------
// QKV projection, 128x128 tile (m97 geometry): BK=64, 4 waves (2x2), each
// wave 64x64 = 4x4 frags. f32 A reg-staged w/ convert; bf16 W via gl2lds.
// Q output (z==0) pre-scaled by 0.125*log2(e): scores land in log2 domain.
// ---------------------------------------------------------------------------
__global__ __launch_bounds__(256) void qkv_proj(const float* __restrict__ q_in,
                                                const float* __restrict__ k_in,
                                                const float* __restrict__ v_in,
                                                const unsigned short* __restrict__ W16,
                                                const float* __restrict__ bq,
                                                const float* __restrict__ bk,
                                                const float* __restrict__ bv,
                                                unsigned short* __restrict__ Q16,
                                                unsigned short* __restrict__ K16,
                                                unsigned short* __restrict__ V16) {
  const int z = blockIdx.z;
  const float* A = z == 0 ? q_in : z == 1 ? k_in : v_in;
  const unsigned short* Bt = W16 + (size_t)z * 1048576;
  const float* bias = z == 0 ? bq : z == 1 ? bk : bv;
  unsigned short* C = z == 0 ? Q16 : z == 1 ? K16 : V16;
  const float oscale = z == 0 ? 0.18033688f : 1.0f;  // 0.125 * log2(e)
  const int K = 1024, N = 1024;

  __shared__ __align__(16) char lds[32768];  // As 16KB | Bs 16KB
  char* As = lds;
  char* Bs = lds + 16384;
  const int tid = threadIdx.x;
  const int lane = tid & 63;
  const int wv = tid >> 6;
  const int g = lane >> 4, r = lane & 15;
  const int wm = wv >> 1, wn = wv & 1;
  const int m0 = blockIdx.y * 128, n0 = blockIdx.x * 128;

  f32x4 acc[4][4];
#pragma unroll
  for (int m = 0; m < 4; ++m)
#pragma unroll
    for (int n = 0; n < 4; ++n) acc[m][n] = (f32x4){0.f, 0.f, 0.f, 0.f};

  for (int k0 = 0; k0 < K; k0 += 64) {
    __syncthreads();
#pragma unroll
    for (int i = 0; i < 4; ++i) {
      int c = (wv * 4 + i) * 64 + lane;  // 0..1023
      int row = c >> 3;
      gl2lds16(Bt + (size_t)(n0 + row) * K + k0 + (c & 7) * 8, Bs + (wv * 4 + i) * 1024);
    }
#pragma unroll
    for (int i = 0; i < 4; ++i) {
      int c = tid + i * 256;
      int row = c >> 3, e = (c & 7) * 8;
      load8cv(A + (size_t)(m0 + row) * K + k0 + e, As + c * 16);
    }
    __syncthreads();
#pragma unroll
    for (int kk = 0; kk < 2; ++kk) {
      short8 af[4], bfr[4];
#pragma unroll
      for (int m = 0; m < 4; ++m)
        af[m] = *(const short8*)(As + (wm * 64 + m * 16 + r) * 128 + kk * 64 + g * 16);
#pragma unroll
      for (int n = 0; n < 4; ++n)
        bfr[n] = *(const short8*)(Bs + (wn * 64 + n * 16 + r) * 128 + kk * 64 + g * 16);
#pragma unroll
      for (int m = 0; m < 4; ++m)
#pragma unroll
        for (int n = 0; n < 4; ++n) acc[m][n] = MFMA16(af[m], bfr[n], acc[m][n]);
    }
  }

#pragma unroll
  for (int n = 0; n < 4; ++n) {
    int col = n0 + wn * 64 + n * 16 + r;
    float bv_ = bias[col];
#pragma unroll
    for (int m = 0; m < 4; ++m)
#pragma unroll
      for (int i = 0; i < 4; ++i) {
        int rowg = m0 + wm * 64 + m * 16 + 4 * g + i;
        C[(size_t)rowg * N + col] = f2bf((acc[m][n][i] + bv_) * oscale);
      }
  }
}

// ---------------------------------------------------------------------------
__global__ __launch_bounds__(256) void o_proj(const unsigned short* __restrict__ A,
                                              const unsigned short* __restrict__ Bt,
                                              const float* __restrict__ bias,
                                              float* __restrict__ C) {
  const int K = 1024, N = 1024;
  __shared__ __align__(16) char lds[24576];
  char* As = lds;
  char* Bs = lds + 16384;
  const int tid = threadIdx.x;
  const int lane = tid & 63;
  const int wv = tid >> 6;
  const int g = lane >> 4, r = lane & 15;
  const int wm = wv >> 1, wn = wv & 1;
  const int m0 = blockIdx.y * 128, n0 = blockIdx.x * 64;

  f32x4 acc[4][2];
#pragma unroll
  for (int m = 0; m < 4; ++m)
#pragma unroll
    for (int n = 0; n < 2; ++n) acc[m][n] = (f32x4){0.f, 0.f, 0.f, 0.f};

  for (int k0 = 0; k0 < K; k0 += 64) {
    __syncthreads();
#pragma unroll
    for (int i = 0; i < 2; ++i) {
      int c = (wv * 2 + i) * 64 + lane;
      int row = c >> 3;
      gl2lds16(Bt + (size_t)(n0 + row) * K + k0 + (c & 7) * 8, Bs + (wv * 2 + i) * 1024);
    }
#pragma unroll
    for (int i = 0; i < 4; ++i) {
      int c = (wv * 4 + i) * 64 + lane;
      int row = c >> 3;
      gl2lds16(A + (size_t)(m0 + row) * K + k0 + (c & 7) * 8, As + (wv * 4 + i) * 1024);
    }
    __syncthreads();
#pragma unroll
    for (int kk = 0; kk < 2; ++kk) {
      short8 af[4], bfr[2];
#pragma unroll
      for (int m = 0; m < 4; ++m)
        af[m] = *(const short8*)(As + (wm * 64 + m * 16 + r) * 128 + kk * 64 + g * 16);
#pragma unroll
      for (int n = 0; n < 2; ++n)
        bfr[n] = *(const short8*)(Bs + (wn * 32 + n * 16 + r) * 128 + kk * 64 + g * 16);
#pragma unroll
      for (int m = 0; m < 4; ++m)
#pragma unroll
        for (int n = 0; n < 2; ++n) acc[m][n] = MFMA16(af[m], bfr[n], acc[m][n]);
    }
  }

#pragma unroll
  for (int n = 0; n < 2; ++n) {
    int col = n0 + wn * 32 + n * 16 + r;
    float bv_ = bias[col];
#pragma unroll
    for (int m = 0; m < 4; ++m)
#pragma unroll
      for (int i = 0; i < 4; ++i) {
        int rowg = m0 + wm * 64 + m * 16 + 4 * g + i;
        C[(size_t)rowg * N + col] = acc[m][n][i] + bv_;
      }
  }
}

// ---------------------------------------------------------------------------
__global__ __launch_bounds__(256) void transpose_v(const unsigned short* __restrict__ V,
                                                   unsigned short* __restrict__ Vt) {
  int t = blockIdx.x * 256 + threadIdx.x;
  int d = t & 63;
  int sc = (t >> 6) & 255;
  int bh = t >> 14;
  int b = bh >> 4, h = bh & 15;
  unsigned short vals[8];
#pragma unroll
  for (int j = 0; j < 8; ++j)
    vals[j] = V[(size_t)(b * 2048 + sc * 8 + j) * 1024 + h * 64 + d];
  *(short8*)&Vt[((size_t)bh * 64 + d) * 2048 + sc * 8] = *(short8*)vals;
}

// ---------------------------------------------------------------------------
// Fused attention v10: exp2 domain (Q pre-scaled by log2e/8), EXP2/LOG2
// builtins; nt attention stores; setprio PV; round-7 pipeline geometry.
// ---------------------------------------------------------------------------
__global__ __launch_bounds__(256, 4) void attn_fused(const unsigned short* __restrict__ Q,
                                                     const unsigned short* __restrict__ K,
                                                     const unsigned short* __restrict__ Vt,
                                                     float* __restrict__ attn,
                                                     unsigned short* __restrict__ O) {
  __shared__ __align__(16) char lds[40960];  // dbuf 2x16KB | pbuf 4x2KB
  const int tid = threadIdx.x;
  const int lane = tid & 63;
  const int wv = tid >> 6;
  const int g = lane >> 4, r = lane & 15;
  int nb = (blockIdx.x & 7) * 128 + (blockIdx.x >> 3);
  const int qt = nb & 31, bh = nb >> 5, h = bh & 15, b = bh >> 4;
  const int qloc = qt * 64 + wv * 16;
  const int qrow0 = b * 2048 + qloc;
  const unsigned short* Kbh = K + (size_t)b * 2048 * 1024 + h * 64;
  const unsigned short* Vbh = Vt + (size_t)bh * 64 * 2048;
  float* attn_bh = attn + (size_t)bh * 2048 * 2048;
  char* pb = lds + 32768 + wv * 2048;
  const int swr = (r & 7) << 4;

  short8 qf[2];
#pragma unroll
  for (int kk = 0; kk < 2; ++kk)
    qf[kk] = *(const short8*)&Q[(size_t)(qrow0 + r) * 1024 + h * 64 + kk * 32 + g * 8];

#define P1_ISSUE(bb, ktt)                                                      \
  do {                                                                         \
    _Pragma("unroll") for (int i_ = 0; i_ < 4; ++i_) {                         \
      int c_ = (wv * 4 + i_) * 64 + lane;                                      \
      int kr_ = c_ >> 3;                                                       \
      int scb_ = ((c_ & 7) * 16) ^ ((kr_ & 7) << 4);                           \
      gl2lds16(Kbh + (size_t)((ktt) + kr_) * 1024 + (scb_ >> 1),               \
               (bb) + (wv * 4 + i_) * 1024);                                   \
    }                                                                          \
  } while (0)
#define P2_ISSUE(bb, ktt)                                                      \
  do {                                                                         \
    _Pragma("unroll") for (int i_ = 0; i_ < 4; ++i_) {                         \
      int c_ = (wv * 4 + i_) * 64 + lane;                                      \
      int kr_ = (c_ >> 3) & 63;                                                \
      int scb_ = ((c_ & 7) * 16) ^ ((kr_ & 7) << 4);                           \
      const unsigned short* src_ =                                             \
          (c_ < 512) ? (Kbh + (size_t)((ktt) + kr_) * 1024 + (scb_ >> 1))      \
                     : (Vbh + (size_t)kr_ * 2048 + (ktt) + (scb_ >> 1));       \
      gl2lds16(src_, (bb) + (wv * 4 + i_) * 1024);                             \
    }                                                                          \
  } while (0)

  // ---------------- pass 1: per-lane exp2-sum (swapped layout), KVBLK=128 ---
  float lrow = 0.f;
  int cur = 0;
  P1_ISSUE(lds, 0);
  for (int t = 0; t < 16; ++t) {
    char* bcur = lds + (cur << 14);
    char* bnxt = lds + ((cur ^ 1) << 14);
    if (t < 15) {
      P1_ISSUE(bnxt, (t + 1) * 128);
      BAR_V4;
    } else {
      BAR_V0;
    }
#pragma unroll
    for (int ct = 0; ct < 8; ++ct) {
      int row = ct * 16 + r;
      int sw = (row & 7) << 4;
      short8 kf0 = *(const short8*)(bcur + ((row * 128 + g * 16) ^ sw));
      short8 kf1 = *(const short8*)(bcur + ((row * 128 + 64 + g * 16) ^ sw));
      f32x4 s = (f32x4){0.f, 0.f, 0.f, 0.f};
      s = MFMA16(kf0, qf[0], s);
      s = MFMA16(kf1, qf[1], s);
      lrow += (EXP2(s[0]) + EXP2(s[1])) + (EXP2(s[2]) + EXP2(s[3]));
    }
    BAR_RAW;
    cur ^= 1;
  }
  lrow += __shfl_xor(lrow, 16);
  lrow += __shfl_xor(lrow, 32);
  const float negml = -LOG2(lrow);
  const f32x4 cinit = (f32x4){negml, negml, negml, negml};

  // ---------------- pass 2: direct nt-store + PV, KVBLK=64 ------------------
  f32x4 oacc[4];
#pragma unroll
  for (int i = 0; i < 4; ++i) oacc[i] = (f32x4){0.f, 0.f, 0.f, 0.f};

  float* arow = attn_bh + (size_t)(qloc + r) * 2048 + 4 * g;
  cur = 0;
  P2_ISSUE(lds, 0);
  for (int t = 0; t < 32; ++t) {
    char* bcur = lds + (cur << 14);
    char* bnxt = lds + ((cur ^ 1) << 14);
    int kt = t * 64;
    if (t < 31) {
      P2_ISSUE(bnxt, kt + 64);
      BAR_V4;
    } else {
      BAR_V0;
    }
    // QK^T (C-init = -log2 l) -> p = exp2(s) already normalized
#pragma unroll
    for (int ct = 0; ct < 4; ++ct) {
      int row = ct * 16 + r;
      int sw = (row & 7) << 4;
      short8 kf0 = *(const short8*)(bcur + ((row * 128 + g * 16) ^ sw));
      short8 kf1 = *(const short8*)(bcur + ((row * 128 + 64 + g * 16) ^ sw));
      f32x4 s = MFMA16(kf0, qf[0], cinit);
      s = MFMA16(kf1, qf[1], s);
      f32x4 p;
      p[0] = EXP2(s[0]); p[1] = EXP2(s[1]);
      p[2] = EXP2(s[2]); p[3] = EXP2(s[3]);
      __builtin_nontemporal_store(p, (f32x4*)(arow + kt + 16 * ct));
      u32x2 pk;
      pk[0] = cvtpk(p[0], p[1]);
      pk[1] = cvtpk(p[2], p[3]);
      *(u32x2*)(pb + ((r * 128 + (ct * 16 + 4 * g) * 2) ^ swr)) = pk;
    }
    // PV cluster
    __builtin_amdgcn_s_setprio(1);
#pragma unroll
    for (int kk2 = 0; kk2 < 2; ++kk2) {
      short8 pa = *(const short8*)(pb + ((r * 128 + kk2 * 64 + g * 16) ^ swr));
#pragma unroll
      for (int ct2 = 0; ct2 < 4; ++ct2) {
        int vrow = ct2 * 16 + r;
        short8 vf = *(const short8*)(bcur + 8192 +
                                     ((vrow * 128 + kk2 * 64 + g * 16) ^ ((vrow & 7) << 4)));
        oacc[ct2] = MFMA16(pa, vf, oacc[ct2]);
      }
    }
    __builtin_amdgcn_s_setprio(0);
    BAR_RAW;
    cur ^= 1;
  }
#pragma unroll
  for (int ct2 = 0; ct2 < 4; ++ct2)
#pragma unroll
    for (int i = 0; i < 4; ++i)
      O[(size_t)(qrow0 + 4 * g + i) * 1024 + h * 64 + ct2 * 16 + r] = f2bf(oacc[ct2][i]);
#undef P1_ISSUE
#undef P2_ISSUE
}

// ---------------------------------------------------------------------------
extern "C" void kernel_launch(void* const* d_in, const int* in_sizes, int n_in,
                              void* d_out, int out_size, void* d_ws, size_t ws_size,
                              hipStream_t stream) {
  const float* q_in = (const float*)d_in[0];
  const float* k_in = (const float*)d_in[1];
  const float* v_in = (const float*)d_in[2];
  const float* wq = (const float*)d_in[3];
  const float* bq = (const float*)d_in[4];
  const float* wk = (const float*)d_in[5];
  const float* bk = (const float*)d_in[6];
  const float* wv = (const float*)d_in[7];
  const float* bv = (const float*)d_in[8];
  const float* wo = (const float*)d_in[9];
  const float* bo = (const float*)d_in[10];

  char* ws = (char*)d_ws;
  const size_t MB8 = 8ull * 1024 * 1024;
  unsigned short* W16 = (unsigned short*)(ws);
  unsigned short* Q16 = (unsigned short*)(ws + MB8);
  unsigned short* K16 = (unsigned short*)(ws + 2 * MB8);
  unsigned short* V16 = (unsigned short*)(ws + 3 * MB8);
  unsigned short* Vt  = (unsigned short*)(ws + 4 * MB8);
  unsigned short* O16 = (unsigned short*)(ws + 3 * MB8);  // alias V16 (dead after transpose)

  float* out = (float*)d_out;
  float* attn = out + 4194304ull;

  dim3 blk(256);
  cast_weights<<<dim3(2048), blk, 0, stream>>>(wq, wk, wv, wo, W16);
  qkv_proj<<<dim3(8, 32, 3), blk, 0, stream>>>(q_in, k_in, v_in, W16, bq, bk, bv, Q16, K16, V16);
  transpose_v<<<dim3(2048), blk, 0, stream>>>(V16, Vt);
  attn_fused<<<dim3(1024), blk, 0, stream>>>(Q16, K16, Vt, attn, O16);
  o_proj<<<dim3(16, 32), blk, 0, stream>>>(O16, W16 + 3145728, bo, out);
}

// Round 12
// 293.418 us; speedup vs baseline: 1.1200x; 1.0107x over previous
//
#include <hip/hip_runtime.h>
#include <stdint.h>

typedef __attribute__((ext_vector_type(4))) float f32x4;
typedef __attribute__((ext_vector_type(8))) short short8;
typedef __attribute__((ext_vector_type(2))) unsigned int u32x2;

#define MFMA16(a, b, c) __builtin_amdgcn_mfma_f32_16x16x32_bf16((a), (b), (c), 0, 0, 0)
#define EXP2(x) __builtin_amdgcn_exp2f(x)   // v_exp_f32: 2^x native
#define LOG2(x) __builtin_amdgcn_logf(x)    // v_log_f32: log2 native

__device__ __forceinline__ unsigned short f2bf(float f) {
  unsigned int x = __float_as_uint(f);
  return (unsigned short)((x + 0x7fffu + ((x >> 16) & 1u)) >> 16);
}

__device__ __forceinline__ unsigned int cvtpk(float lo, float hi) {
  unsigned int d;
  asm("v_cvt_pk_bf16_f32 %0, %1, %2" : "=v"(d) : "v"(lo), "v"(hi));
  return d;
}

__device__ __forceinline__ void gl2lds16(const void* g, void* l) {
  __builtin_amdgcn_global_load_lds((const __attribute__((address_space(1))) void*)g,
                                   (__attribute__((address_space(3))) void*)l, 16, 0, 0);
}

__device__ __forceinline__ void load8cv(const float* __restrict__ s, void* d) {
  const f32x4* p = (const f32x4*)s;
  f32x4 a = p[0], b = p[1];
  short8 t;
  t[0] = (short)f2bf(a[0]); t[1] = (short)f2bf(a[1]);
  t[2] = (short)f2bf(a[2]); t[3] = (short)f2bf(a[3]);
  t[4] = (short)f2bf(b[0]); t[5] = (short)f2bf(b[1]);
  t[6] = (short)f2bf(b[2]); t[7] = (short)f2bf(b[3]);
  *(short8*)d = t;
}

#define BAR_V4 asm volatile("s_waitcnt vmcnt(4)\ns_barrier" ::: "memory")
// vmcnt is ONE in-order queue of loads+stores. Steady-state pass-2 queue:
// [gl2lds(t):4][nt-stores(t-1):16][gl2lds(t+1):4] = 24. vmcnt(20) retires
// exactly the 4 gl2lds(t) we need -- nt-stores get ~2 tiles of slack
// instead of a per-tile HBM-store-retirement drain.
#define BAR_V20 asm volatile("s_waitcnt vmcnt(20)\ns_barrier" ::: "memory")
#define BAR_V0 asm volatile("s_waitcnt vmcnt(0)\ns_barrier" ::: "memory")
#define BAR_RAW asm volatile("s_barrier" ::: "memory")

// ---------------------------------------------------------------------------
__global__ __launch_bounds__(256) void cast_weights(const float* __restrict__ wq,
                                                    const float* __restrict__ wk,
                                                    const float* __restrict__ wv,
                                                    const float* __restrict__ wo,
                                                    unsigned short* __restrict__ dst) {
  int i = blockIdx.x * 256 + threadIdx.x;
  int which = i >> 17;
  int off = (i & 131071) * 8;
  const float* src = which == 0 ? wq : which == 1 ? wk : which == 2 ? wv : wo;
  load8cv(src + off, dst + (size_t)which * 1048576 + off);
}

// ---------------------------------------------------------------------------
// QKV projection, 128x128 tile: BK=64, 4 waves (2x2), 4x4 frags.
// Q output (z==0) pre-scaled by 0.125*log2(e): scores land in log2 domain.
// ---------------------------------------------------------------------------
__global__ __launch_bounds__(256) void qkv_proj(const float* __restrict__ q_in,
                                                const float* __restrict__ k_in,
                                                const float* __restrict__ v_in,
                                                const unsigned short* __restrict__ W16,
                                                const float* __restrict__ bq,
                                                const float* __restrict__ bk,
                                                const float* __restrict__ bv,
                                                unsigned short* __restrict__ Q16,
                                                unsigned short* __restrict__ K16,
                                                unsigned short* __restrict__ V16) {
  const int z = blockIdx.z;
  const float* A = z == 0 ? q_in : z == 1 ? k_in : v_in;
  const unsigned short* Bt = W16 + (size_t)z * 1048576;
  const float* bias = z == 0 ? bq : z == 1 ? bk : bv;
  unsigned short* C = z == 0 ? Q16 : z == 1 ? K16 : V16;
  const float oscale = z == 0 ? 0.18033688f : 1.0f;  // 0.125 * log2(e)
  const int K = 1024, N = 1024;

  __shared__ __align__(16) char lds[32768];  // As 16KB | Bs 16KB
  char* As = lds;
  char* Bs = lds + 16384;
  const int tid = threadIdx.x;
  const int lane = tid & 63;
  const int wv = tid >> 6;
  const int g = lane >> 4, r = lane & 15;
  const int wm = wv >> 1, wn = wv & 1;
  const int m0 = blockIdx.y * 128, n0 = blockIdx.x * 128;

  f32x4 acc[4][4];
#pragma unroll
  for (int m = 0; m < 4; ++m)
#pragma unroll
    for (int n = 0; n < 4; ++n) acc[m][n] = (f32x4){0.f, 0.f, 0.f, 0.f};

  for (int k0 = 0; k0 < K; k0 += 64) {
    __syncthreads();
#pragma unroll
    for (int i = 0; i < 4; ++i) {
      int c = (wv * 4 + i) * 64 + lane;  // 0..1023
      int row = c >> 3;
      gl2lds16(Bt + (size_t)(n0 + row) * K + k0 + (c & 7) * 8, Bs + (wv * 4 + i) * 1024);
    }
#pragma unroll
    for (int i = 0; i < 4; ++i) {
      int c = tid + i * 256;
      int row = c >> 3, e = (c & 7) * 8;
      load8cv(A + (size_t)(m0 + row) * K + k0 + e, As + c * 16);
    }
    __syncthreads();
#pragma unroll
    for (int kk = 0; kk < 2; ++kk) {
      short8 af[4], bfr[4];
#pragma unroll
      for (int m = 0; m < 4; ++m)
        af[m] = *(const short8*)(As + (wm * 64 + m * 16 + r) * 128 + kk * 64 + g * 16);
#pragma unroll
      for (int n = 0; n < 4; ++n)
        bfr[n] = *(const short8*)(Bs + (wn * 64 + n * 16 + r) * 128 + kk * 64 + g * 16);
#pragma unroll
      for (int m = 0; m < 4; ++m)
#pragma unroll
        for (int n = 0; n < 4; ++n) acc[m][n] = MFMA16(af[m], bfr[n], acc[m][n]);
    }
  }

#pragma unroll
  for (int n = 0; n < 4; ++n) {
    int col = n0 + wn * 64 + n * 16 + r;
    float bv_ = bias[col];
#pragma unroll
    for (int m = 0; m < 4; ++m)
#pragma unroll
      for (int i = 0; i < 4; ++i) {
        int rowg = m0 + wm * 64 + m * 16 + 4 * g + i;
        C[(size_t)rowg * N + col] = f2bf((acc[m][n][i] + bv_) * oscale);
      }
  }
}

// ---------------------------------------------------------------------------
__global__ __launch_bounds__(256) void o_proj(const unsigned short* __restrict__ A,
                                              const unsigned short* __restrict__ Bt,
                                              const float* __restrict__ bias,
                                              float* __restrict__ C) {
  const int K = 1024, N = 1024;
  __shared__ __align__(16) char lds[24576];
  char* As = lds;
  char* Bs = lds + 16384;
  const int tid = threadIdx.x;
  const int lane = tid & 63;
  const int wv = tid >> 6;
  const int g = lane >> 4, r = lane & 15;
  const int wm = wv >> 1, wn = wv & 1;
  const int m0 = blockIdx.y * 128, n0 = blockIdx.x * 64;

  f32x4 acc[4][2];
#pragma unroll
  for (int m = 0; m < 4; ++m)
#pragma unroll
    for (int n = 0; n < 2; ++n) acc[m][n] = (f32x4){0.f, 0.f, 0.f, 0.f};

  for (int k0 = 0; k0 < K; k0 += 64) {
    __syncthreads();
#pragma unroll
    for (int i = 0; i < 2; ++i) {
      int c = (wv * 2 + i) * 64 + lane;
      int row = c >> 3;
      gl2lds16(Bt + (size_t)(n0 + row) * K + k0 + (c & 7) * 8, Bs + (wv * 2 + i) * 1024);
    }
#pragma unroll
    for (int i = 0; i < 4; ++i) {
      int c = (wv * 4 + i) * 64 + lane;
      int row = c >> 3;
      gl2lds16(A + (size_t)(m0 + row) * K + k0 + (c & 7) * 8, As + (wv * 4 + i) * 1024);
    }
    __syncthreads();
#pragma unroll
    for (int kk = 0; kk < 2; ++kk) {
      short8 af[4], bfr[2];
#pragma unroll
      for (int m = 0; m < 4; ++m)
        af[m] = *(const short8*)(As + (wm * 64 + m * 16 + r) * 128 + kk * 64 + g * 16);
#pragma unroll
      for (int n = 0; n < 2; ++n)
        bfr[n] = *(const short8*)(Bs + (wn * 32 + n * 16 + r) * 128 + kk * 64 + g * 16);
#pragma unroll
      for (int m = 0; m < 4; ++m)
#pragma unroll
        for (int n = 0; n < 2; ++n) acc[m][n] = MFMA16(af[m], bfr[n], acc[m][n]);
    }
  }

#pragma unroll
  for (int n = 0; n < 2; ++n) {
    int col = n0 + wn * 32 + n * 16 + r;
    float bv_ = bias[col];
#pragma unroll
    for (int m = 0; m < 4; ++m)
#pragma unroll
      for (int i = 0; i < 4; ++i) {
        int rowg = m0 + wm * 64 + m * 16 + 4 * g + i;
        C[(size_t)rowg * N + col] = acc[m][n][i] + bv_;
      }
  }
}

// ---------------------------------------------------------------------------
__global__ __launch_bounds__(256) void transpose_v(const unsigned short* __restrict__ V,
                                                   unsigned short* __restrict__ Vt) {
  int t = blockIdx.x * 256 + threadIdx.x;
  int d = t & 63;
  int sc = (t >> 6) & 255;
  int bh = t >> 14;
  int b = bh >> 4, h = bh & 15;
  unsigned short vals[8];
#pragma unroll
  for (int j = 0; j < 8; ++j)
    vals[j] = V[(size_t)(b * 2048 + sc * 8 + j) * 1024 + h * 64 + d];
  *(short8*)&Vt[((size_t)bh * 64 + d) * 2048 + sc * 8] = *(short8*)vals;
}

// ---------------------------------------------------------------------------
// Fused attention v12 = v10 + store-aware counted vmcnt (BAR_V20): the
// barrier no longer drains the previous tile's 16 nt-stores, only the 4
// gl2lds it actually depends on.
// ---------------------------------------------------------------------------
__global__ __launch_bounds__(256, 4) void attn_fused(const unsigned short* __restrict__ Q,
                                                     const unsigned short* __restrict__ K,
                                                     const unsigned short* __restrict__ Vt,
                                                     float* __restrict__ attn,
                                                     unsigned short* __restrict__ O) {
  __shared__ __align__(16) char lds[40960];  // dbuf 2x16KB | pbuf 4x2KB
  const int tid = threadIdx.x;
  const int lane = tid & 63;
  const int wv = tid >> 6;
  const int g = lane >> 4, r = lane & 15;
  int nb = (blockIdx.x & 7) * 128 + (blockIdx.x >> 3);
  const int qt = nb & 31, bh = nb >> 5, h = bh & 15, b = bh >> 4;
  const int qloc = qt * 64 + wv * 16;
  const int qrow0 = b * 2048 + qloc;
  const unsigned short* Kbh = K + (size_t)b * 2048 * 1024 + h * 64;
  const unsigned short* Vbh = Vt + (size_t)bh * 64 * 2048;
  float* attn_bh = attn + (size_t)bh * 2048 * 2048;
  char* pb = lds + 32768 + wv * 2048;
  const int swr = (r & 7) << 4;

  short8 qf[2];
#pragma unroll
  for (int kk = 0; kk < 2; ++kk)
    qf[kk] = *(const short8*)&Q[(size_t)(qrow0 + r) * 1024 + h * 64 + kk * 32 + g * 8];

#define P1_ISSUE(bb, ktt)                                                      \
  do {                                                                         \
    _Pragma("unroll") for (int i_ = 0; i_ < 4; ++i_) {                         \
      int c_ = (wv * 4 + i_) * 64 + lane;                                      \
      int kr_ = c_ >> 3;                                                       \
      int scb_ = ((c_ & 7) * 16) ^ ((kr_ & 7) << 4);                           \
      gl2lds16(Kbh + (size_t)((ktt) + kr_) * 1024 + (scb_ >> 1),               \
               (bb) + (wv * 4 + i_) * 1024);                                   \
    }                                                                          \
  } while (0)
#define P2_ISSUE(bb, ktt)                                                      \
  do {                                                                         \
    _Pragma("unroll") for (int i_ = 0; i_ < 4; ++i_) {                         \
      int c_ = (wv * 4 + i_) * 64 + lane;                                      \
      int kr_ = (c_ >> 3) & 63;                                                \
      int scb_ = ((c_ & 7) * 16) ^ ((kr_ & 7) << 4);                           \
      const unsigned short* src_ =                                             \
          (c_ < 512) ? (Kbh + (size_t)((ktt) + kr_) * 1024 + (scb_ >> 1))      \
                     : (Vbh + (size_t)kr_ * 2048 + (ktt) + (scb_ >> 1));       \
      gl2lds16(src_, (bb) + (wv * 4 + i_) * 1024);                             \
    }                                                                          \
  } while (0)

  // ---------------- pass 1: per-lane exp2-sum (swapped layout), KVBLK=128 ---
  float lrow = 0.f;
  int cur = 0;
  P1_ISSUE(lds, 0);
  for (int t = 0; t < 16; ++t) {
    char* bcur = lds + (cur << 14);
    char* bnxt = lds + ((cur ^ 1) << 14);
    if (t < 15) {
      P1_ISSUE(bnxt, (t + 1) * 128);
      BAR_V4;
    } else {
      BAR_V0;
    }
#pragma unroll
    for (int ct = 0; ct < 8; ++ct) {
      int row = ct * 16 + r;
      int sw = (row & 7) << 4;
      short8 kf0 = *(const short8*)(bcur + ((row * 128 + g * 16) ^ sw));
      short8 kf1 = *(const short8*)(bcur + ((row * 128 + 64 + g * 16) ^ sw));
      f32x4 s = (f32x4){0.f, 0.f, 0.f, 0.f};
      s = MFMA16(kf0, qf[0], s);
      s = MFMA16(kf1, qf[1], s);
      lrow += (EXP2(s[0]) + EXP2(s[1])) + (EXP2(s[2]) + EXP2(s[3]));
    }
    BAR_RAW;
    cur ^= 1;
  }
  lrow += __shfl_xor(lrow, 16);
  lrow += __shfl_xor(lrow, 32);
  const float negml = -LOG2(lrow);
  const f32x4 cinit = (f32x4){negml, negml, negml, negml};

  // ---------------- pass 2: direct nt-store + PV, KVBLK=64 ------------------
  f32x4 oacc[4];
#pragma unroll
  for (int i = 0; i < 4; ++i) oacc[i] = (f32x4){0.f, 0.f, 0.f, 0.f};

  float* arow = attn_bh + (size_t)(qloc + r) * 2048 + 4 * g;
  cur = 0;
  P2_ISSUE(lds, 0);
  for (int t = 0; t < 32; ++t) {
    char* bcur = lds + (cur << 14);
    char* bnxt = lds + ((cur ^ 1) << 14);
    int kt = t * 64;
    if (t < 31) {
      P2_ISSUE(bnxt, kt + 64);
      if (t == 0) {
        BAR_V4;   // no stores in flight yet
      } else {
        BAR_V20;  // retire only stage(t)'s 4 gl2lds; stores keep flowing
      }
    } else {
      BAR_V0;
    }
    // QK^T (C-init = -log2 l) -> p = exp2(s) already normalized
#pragma unroll
    for (int ct = 0; ct < 4; ++ct) {
      int row = ct * 16 + r;
      int sw = (row & 7) << 4;
      short8 kf0 = *(const short8*)(bcur + ((row * 128 + g * 16) ^ sw));
      short8 kf1 = *(const short8*)(bcur + ((row * 128 + 64 + g * 16) ^ sw));
      f32x4 s = MFMA16(kf0, qf[0], cinit);
      s = MFMA16(kf1, qf[1], s);
      f32x4 p;
      p[0] = EXP2(s[0]); p[1] = EXP2(s[1]);
      p[2] = EXP2(s[2]); p[3] = EXP2(s[3]);
      __builtin_nontemporal_store(p, (f32x4*)(arow + kt + 16 * ct));
      u32x2 pk;
      pk[0] = cvtpk(p[0], p[1]);
      pk[1] = cvtpk(p[2], p[3]);
      *(u32x2*)(pb + ((r * 128 + (ct * 16 + 4 * g) * 2) ^ swr)) = pk;
    }
    // PV cluster
    __builtin_amdgcn_s_setprio(1);
#pragma unroll
    for (int kk2 = 0; kk2 < 2; ++kk2) {
      short8 pa = *(const short8*)(pb + ((r * 128 + kk2 * 64 + g * 16) ^ swr));
#pragma unroll
      for (int ct2 = 0; ct2 < 4; ++ct2) {
        int vrow = ct2 * 16 + r;
        short8 vf = *(const short8*)(bcur + 8192 +
                                     ((vrow * 128 + kk2 * 64 + g * 16) ^ ((vrow & 7) << 4)));
        oacc[ct2] = MFMA16(pa, vf, oacc[ct2]);
      }
    }
    __builtin_amdgcn_s_setprio(0);
    BAR_RAW;
    cur ^= 1;
  }
#pragma unroll
  for (int ct2 = 0; ct2 < 4; ++ct2)
#pragma unroll
    for (int i = 0; i < 4; ++i)
      O[(size_t)(qrow0 + 4 * g + i) * 1024 + h * 64 + ct2 * 16 + r] = f2bf(oacc[ct2][i]);
#undef P1_ISSUE
#undef P2_ISSUE
}

// ---------------------------------------------------------------------------
extern "C" void kernel_launch(void* const* d_in, const int* in_sizes, int n_in,
                              void* d_out, int out_size, void* d_ws, size_t ws_size,
                              hipStream_t stream) {
  const float* q_in = (const float*)d_in[0];
  const float* k_in = (const float*)d_in[1];
  const float* v_in = (const float*)d_in[2];
  const float* wq = (const float*)d_in[3];
  const float* bq = (const float*)d_in[4];
  const float* wk = (const float*)d_in[5];
  const float* bk = (const float*)d_in[6];
  const float* wv = (const float*)d_in[7];
  const float* bv = (const float*)d_in[8];
  const float* wo = (const float*)d_in[9];
  const float* bo = (const float*)d_in[10];

  char* ws = (char*)d_ws;
  const size_t MB8 = 8ull * 1024 * 1024;
  unsigned short* W16 = (unsigned short*)(ws);
  unsigned short* Q16 = (unsigned short*)(ws + MB8);
  unsigned short* K16 = (unsigned short*)(ws + 2 * MB8);
  unsigned short* V16 = (unsigned short*)(ws + 3 * MB8);
  unsigned short* Vt  = (unsigned short*)(ws + 4 * MB8);
  unsigned short* O16 = (unsigned short*)(ws + 3 * MB8);  // alias V16 (dead after transpose)

  float* out = (float*)d_out;
  float* attn = out + 4194304ull;

  dim3 blk(256);
  cast_weights<<<dim3(2048), blk, 0, stream>>>(wq, wk, wv, wo, W16);
  qkv_proj<<<dim3(8, 32, 3), blk, 0, stream>>>(q_in, k_in, v_in, W16, bq, bk, bv, Q16, K16, V16);
  transpose_v<<<dim3(2048), blk, 0, stream>>>(V16, Vt);
  attn_fused<<<dim3(1024), blk, 0, stream>>>(Q16, K16, Vt, attn, O16);
  o_proj<<<dim3(16, 32), blk, 0, stream>>>(O16, W16 + 3145728, bo, out);
}

// Round 13
// 290.293 us; speedup vs baseline: 1.1320x; 1.0108x over previous
//
#include <hip/hip_runtime.h>
#include <stdint.h>

typedef __attribute__((ext_vector_type(4))) float f32x4;
typedef __attribute__((ext_vector_type(8))) short short8;
typedef __attribute__((ext_vector_type(2))) unsigned int u32x2;

#define MFMA16(a, b, c) __builtin_amdgcn_mfma_f32_16x16x32_bf16((a), (b), (c), 0, 0, 0)
#define EXP2(x) __builtin_amdgcn_exp2f(x)   // v_exp_f32: 2^x native
#define LOG2(x) __builtin_amdgcn_logf(x)    // v_log_f32: log2 native

__device__ __forceinline__ unsigned short f2bf(float f) {
  unsigned int x = __float_as_uint(f);
  return (unsigned short)((x + 0x7fffu + ((x >> 16) & 1u)) >> 16);
}

__device__ __forceinline__ unsigned int cvtpk(float lo, float hi) {
  unsigned int d;
  asm("v_cvt_pk_bf16_f32 %0, %1, %2" : "=v"(d) : "v"(lo), "v"(hi));
  return d;
}

__device__ __forceinline__ void gl2lds16(const void* g, void* l) {
  __builtin_amdgcn_global_load_lds((const __attribute__((address_space(1))) void*)g,
                                   (__attribute__((address_space(3))) void*)l, 16, 0, 0);
}

__device__ __forceinline__ void load8cv(const float* __restrict__ s, void* d) {
  const f32x4* p = (const f32x4*)s;
  f32x4 a = p[0], b = p[1];
  short8 t;
  t[0] = (short)f2bf(a[0]); t[1] = (short)f2bf(a[1]);
  t[2] = (short)f2bf(a[2]); t[3] = (short)f2bf(a[3]);
  t[4] = (short)f2bf(b[0]); t[5] = (short)f2bf(b[1]);
  t[6] = (short)f2bf(b[2]); t[7] = (short)f2bf(b[3]);
  *(short8*)d = t;
}

#define BAR_V4 asm volatile("s_waitcnt vmcnt(4)\ns_barrier" ::: "memory")
// Pass-2 steady queue (per lane): [gl2lds(t):4][nt-stores(t-1):4][gl2lds(t+1):4]
// = 12 outstanding. vmcnt(8) retires exactly the 4 oldest (stage t).
#define BAR_V8 asm volatile("s_waitcnt vmcnt(8)\ns_barrier" ::: "memory")
#define BAR_V0 asm volatile("s_waitcnt vmcnt(0)\ns_barrier" ::: "memory")
#define BAR_RAW asm volatile("s_barrier" ::: "memory")

// ---------------------------------------------------------------------------
__global__ __launch_bounds__(256) void cast_weights(const float* __restrict__ wq,
                                                    const float* __restrict__ wk,
                                                    const float* __restrict__ wv,
                                                    const float* __restrict__ wo,
                                                    unsigned short* __restrict__ dst) {
  int i = blockIdx.x * 256 + threadIdx.x;
  int which = i >> 17;
  int off = (i & 131071) * 8;
  const float* src = which == 0 ? wq : which == 1 ? wk : which == 2 ? wv : wo;
  load8cv(src + off, dst + (size_t)which * 1048576 + off);
}

// ---------------------------------------------------------------------------
// QKV projection, 128x128 tile: BK=64, 4 waves (2x2), 4x4 frags.
// Q output (z==0) pre-scaled by 0.125*log2(e): scores land in log2 domain.
// ---------------------------------------------------------------------------
__global__ __launch_bounds__(256) void qkv_proj(const float* __restrict__ q_in,
                                                const float* __restrict__ k_in,
                                                const float* __restrict__ v_in,
                                                const unsigned short* __restrict__ W16,
                                                const float* __restrict__ bq,
                                                const float* __restrict__ bk,
                                                const float* __restrict__ bv,
                                                unsigned short* __restrict__ Q16,
                                                unsigned short* __restrict__ K16,
                                                unsigned short* __restrict__ V16) {
  const int z = blockIdx.z;
  const float* A = z == 0 ? q_in : z == 1 ? k_in : v_in;
  const unsigned short* Bt = W16 + (size_t)z * 1048576;
  const float* bias = z == 0 ? bq : z == 1 ? bk : bv;
  unsigned short* C = z == 0 ? Q16 : z == 1 ? K16 : V16;
  const float oscale = z == 0 ? 0.18033688f : 1.0f;  // 0.125 * log2(e)
  const int K = 1024, N = 1024;

  __shared__ __align__(16) char lds[32768];  // As 16KB | Bs 16KB
  char* As = lds;
  char* Bs = lds + 16384;
  const int tid = threadIdx.x;
  const int lane = tid & 63;
  const int wv = tid >> 6;
  const int g = lane >> 4, r = lane & 15;
  const int wm = wv >> 1, wn = wv & 1;
  const int m0 = blockIdx.y * 128, n0 = blockIdx.x * 128;

  f32x4 acc[4][4];
#pragma unroll
  for (int m = 0; m < 4; ++m)
#pragma unroll
    for (int n = 0; n < 4; ++n) acc[m][n] = (f32x4){0.f, 0.f, 0.f, 0.f};

  for (int k0 = 0; k0 < K; k0 += 64) {
    __syncthreads();
#pragma unroll
    for (int i = 0; i < 4; ++i) {
      int c = (wv * 4 + i) * 64 + lane;  // 0..1023
      int row = c >> 3;
      gl2lds16(Bt + (size_t)(n0 + row) * K + k0 + (c & 7) * 8, Bs + (wv * 4 + i) * 1024);
    }
#pragma unroll
    for (int i = 0; i < 4; ++i) {
      int c = tid + i * 256;
      int row = c >> 3, e = (c & 7) * 8;
      load8cv(A + (size_t)(m0 + row) * K + k0 + e, As + c * 16);
    }
    __syncthreads();
#pragma unroll
    for (int kk = 0; kk < 2; ++kk) {
      short8 af[4], bfr[4];
#pragma unroll
      for (int m = 0; m < 4; ++m)
        af[m] = *(const short8*)(As + (wm * 64 + m * 16 + r) * 128 + kk * 64 + g * 16);
#pragma unroll
      for (int n = 0; n < 4; ++n)
        bfr[n] = *(const short8*)(Bs + (wn * 64 + n * 16 + r) * 128 + kk * 64 + g * 16);
#pragma unroll
      for (int m = 0; m < 4; ++m)
#pragma unroll
        for (int n = 0; n < 4; ++n) acc[m][n] = MFMA16(af[m], bfr[n], acc[m][n]);
    }
  }

#pragma unroll
  for (int n = 0; n < 4; ++n) {
    int col = n0 + wn * 64 + n * 16 + r;
    float bv_ = bias[col];
#pragma unroll
    for (int m = 0; m < 4; ++m)
#pragma unroll
      for (int i = 0; i < 4; ++i) {
        int rowg = m0 + wm * 64 + m * 16 + 4 * g + i;
        C[(size_t)rowg * N + col] = f2bf((acc[m][n][i] + bv_) * oscale);
      }
  }
}

// ---------------------------------------------------------------------------
__global__ __launch_bounds__(256) void o_proj(const unsigned short* __restrict__ A,
                                              const unsigned short* __restrict__ Bt,
                                              const float* __restrict__ bias,
                                              float* __restrict__ C) {
  const int K = 1024, N = 1024;
  __shared__ __align__(16) char lds[24576];
  char* As = lds;
  char* Bs = lds + 16384;
  const int tid = threadIdx.x;
  const int lane = tid & 63;
  const int wv = tid >> 6;
  const int g = lane >> 4, r = lane & 15;
  const int wm = wv >> 1, wn = wv & 1;
  const int m0 = blockIdx.y * 128, n0 = blockIdx.x * 64;

  f32x4 acc[4][2];
#pragma unroll
  for (int m = 0; m < 4; ++m)
#pragma unroll
    for (int n = 0; n < 2; ++n) acc[m][n] = (f32x4){0.f, 0.f, 0.f, 0.f};

  for (int k0 = 0; k0 < K; k0 += 64) {
    __syncthreads();
#pragma unroll
    for (int i = 0; i < 2; ++i) {
      int c = (wv * 2 + i) * 64 + lane;
      int row = c >> 3;
      gl2lds16(Bt + (size_t)(n0 + row) * K + k0 + (c & 7) * 8, Bs + (wv * 2 + i) * 1024);
    }
#pragma unroll
    for (int i = 0; i < 4; ++i) {
      int c = (wv * 4 + i) * 64 + lane;
      int row = c >> 3;
      gl2lds16(A + (size_t)(m0 + row) * K + k0 + (c & 7) * 8, As + (wv * 4 + i) * 1024);
    }
    __syncthreads();
#pragma unroll
    for (int kk = 0; kk < 2; ++kk) {
      short8 af[4], bfr[2];
#pragma unroll
      for (int m = 0; m < 4; ++m)
        af[m] = *(const short8*)(As + (wm * 64 + m * 16 + r) * 128 + kk * 64 + g * 16);
#pragma unroll
      for (int n = 0; n < 2; ++n)
        bfr[n] = *(const short8*)(Bs + (wn * 32 + n * 16 + r) * 128 + kk * 64 + g * 16);
#pragma unroll
      for (int m = 0; m < 4; ++m)
#pragma unroll
        for (int n = 0; n < 2; ++n) acc[m][n] = MFMA16(af[m], bfr[n], acc[m][n]);
    }
  }

#pragma unroll
  for (int n = 0; n < 2; ++n) {
    int col = n0 + wn * 32 + n * 16 + r;
    float bv_ = bias[col];
#pragma unroll
    for (int m = 0; m < 4; ++m)
#pragma unroll
      for (int i = 0; i < 4; ++i) {
        int rowg = m0 + wm * 64 + m * 16 + 4 * g + i;
        C[(size_t)rowg * N + col] = acc[m][n][i] + bv_;
      }
  }
}

// ---------------------------------------------------------------------------
__global__ __launch_bounds__(256) void transpose_v(const unsigned short* __restrict__ V,
                                                   unsigned short* __restrict__ Vt) {
  int t = blockIdx.x * 256 + threadIdx.x;
  int d = t & 63;
  int sc = (t >> 6) & 255;
  int bh = t >> 14;
  int b = bh >> 4, h = bh & 15;
  unsigned short vals[8];
#pragma unroll
  for (int j = 0; j < 8; ++j)
    vals[j] = V[(size_t)(b * 2048 + sc * 8 + j) * 1024 + h * 64 + d];
  *(short8*)&Vt[((size_t)bh * 64 + d) * 2048 + sc * 8] = *(short8*)vals;
}

// ---------------------------------------------------------------------------
// Fused attention v13 = v12 with the P LDS round-trip replaced by
// v_permlane{32,16}_swap_b32 in-register redistribution (T12 mechanism):
//   lane (g,r) holds P[q=r][k=16ct+4g+i]; PV needs P[q=r][k=kk2*32+g*8+e].
//   With X=w[2kk2][j], Y=w[2kk2+1][j] (w = cvtpk'd k-pairs):
//     permlane32_swap(X,Y); permlane16_swap(X,Y)
//   => X = [X@g0, X@g2, Y@g0, Y@g2] = pa words m0/m1 (src groups 2(g&1))
//      Y = [X@g1, X@g3, Y@g1, Y@g3] = pa words m2/m3 (src groups 2(g&1)+1)
// Removes 8 ds_write + 2 ds_read + pbuf (LDS 40->32KB) per tile.
// ---------------------------------------------------------------------------
__global__ __launch_bounds__(256, 4) void attn_fused(const unsigned short* __restrict__ Q,
                                                     const unsigned short* __restrict__ K,
                                                     const unsigned short* __restrict__ Vt,
                                                     float* __restrict__ attn,
                                                     unsigned short* __restrict__ O) {
  __shared__ __align__(16) char lds[32768];  // K/V double buffer only
  const int tid = threadIdx.x;
  const int lane = tid & 63;
  const int wv = tid >> 6;
  const int g = lane >> 4, r = lane & 15;
  int nb = (blockIdx.x & 7) * 128 + (blockIdx.x >> 3);
  const int qt = nb & 31, bh = nb >> 5, h = bh & 15, b = bh >> 4;
  const int qloc = qt * 64 + wv * 16;
  const int qrow0 = b * 2048 + qloc;
  const unsigned short* Kbh = K + (size_t)b * 2048 * 1024 + h * 64;
  const unsigned short* Vbh = Vt + (size_t)bh * 64 * 2048;
  float* attn_bh = attn + (size_t)bh * 2048 * 2048;

  short8 qf[2];
#pragma unroll
  for (int kk = 0; kk < 2; ++kk)
    qf[kk] = *(const short8*)&Q[(size_t)(qrow0 + r) * 1024 + h * 64 + kk * 32 + g * 8];

#define P1_ISSUE(bb, ktt)                                                      \
  do {                                                                         \
    _Pragma("unroll") for (int i_ = 0; i_ < 4; ++i_) {                         \
      int c_ = (wv * 4 + i_) * 64 + lane;                                      \
      int kr_ = c_ >> 3;                                                       \
      int scb_ = ((c_ & 7) * 16) ^ ((kr_ & 7) << 4);                           \
      gl2lds16(Kbh + (size_t)((ktt) + kr_) * 1024 + (scb_ >> 1),               \
               (bb) + (wv * 4 + i_) * 1024);                                   \
    }                                                                          \
  } while (0)
#define P2_ISSUE(bb, ktt)                                                      \
  do {                                                                         \
    _Pragma("unroll") for (int i_ = 0; i_ < 4; ++i_) {                         \
      int c_ = (wv * 4 + i_) * 64 + lane;                                      \
      int kr_ = (c_ >> 3) & 63;                                                \
      int scb_ = ((c_ & 7) * 16) ^ ((kr_ & 7) << 4);                           \
      const unsigned short* src_ =                                             \
          (c_ < 512) ? (Kbh + (size_t)((ktt) + kr_) * 1024 + (scb_ >> 1))      \
                     : (Vbh + (size_t)kr_ * 2048 + (ktt) + (scb_ >> 1));       \
      gl2lds16(src_, (bb) + (wv * 4 + i_) * 1024);                             \
    }                                                                          \
  } while (0)

  // ---------------- pass 1: per-lane exp2-sum (swapped layout), KVBLK=128 ---
  float lrow = 0.f;
  int cur = 0;
  P1_ISSUE(lds, 0);
  for (int t = 0; t < 16; ++t) {
    char* bcur = lds + (cur << 14);
    char* bnxt = lds + ((cur ^ 1) << 14);
    if (t < 15) {
      P1_ISSUE(bnxt, (t + 1) * 128);
      BAR_V4;
    } else {
      BAR_V0;
    }
#pragma unroll
    for (int ct = 0; ct < 8; ++ct) {
      int row = ct * 16 + r;
      int sw = (row & 7) << 4;
      short8 kf0 = *(const short8*)(bcur + ((row * 128 + g * 16) ^ sw));
      short8 kf1 = *(const short8*)(bcur + ((row * 128 + 64 + g * 16) ^ sw));
      f32x4 s = (f32x4){0.f, 0.f, 0.f, 0.f};
      s = MFMA16(kf0, qf[0], s);
      s = MFMA16(kf1, qf[1], s);
      lrow += (EXP2(s[0]) + EXP2(s[1])) + (EXP2(s[2]) + EXP2(s[3]));
    }
    BAR_RAW;
    cur ^= 1;
  }
  lrow += __shfl_xor(lrow, 16);
  lrow += __shfl_xor(lrow, 32);
  const float negml = -LOG2(lrow);
  const f32x4 cinit = (f32x4){negml, negml, negml, negml};

  // ---------------- pass 2: nt-store + in-register P redistribute + PV ------
  f32x4 oacc[4];
#pragma unroll
  for (int i = 0; i < 4; ++i) oacc[i] = (f32x4){0.f, 0.f, 0.f, 0.f};

  float* arow = attn_bh + (size_t)(qloc + r) * 2048 + 4 * g;
  cur = 0;
  P2_ISSUE(lds, 0);
  for (int t = 0; t < 32; ++t) {
    char* bcur = lds + (cur << 14);
    char* bnxt = lds + ((cur ^ 1) << 14);
    int kt = t * 64;
    if (t < 31) {
      P2_ISSUE(bnxt, kt + 64);
      if (t == 0) {
        BAR_V4;   // no stores in flight yet
      } else {
        BAR_V8;   // retire stage(t)'s 4 gl2lds; stores(t-1) keep flowing
      }
    } else {
      BAR_V0;
    }
    // QK^T (C-init = -log2 l) -> p = exp2(s) already normalized
    unsigned w[4][2];
#pragma unroll
    for (int ct = 0; ct < 4; ++ct) {
      int row = ct * 16 + r;
      int sw = (row & 7) << 4;
      short8 kf0 = *(const short8*)(bcur + ((row * 128 + g * 16) ^ sw));
      short8 kf1 = *(const short8*)(bcur + ((row * 128 + 64 + g * 16) ^ sw));
      f32x4 s = MFMA16(kf0, qf[0], cinit);
      s = MFMA16(kf1, qf[1], s);
      f32x4 p;
      p[0] = EXP2(s[0]); p[1] = EXP2(s[1]);
      p[2] = EXP2(s[2]); p[3] = EXP2(s[3]);
      __builtin_nontemporal_store(p, (f32x4*)(arow + kt + 16 * ct));
      w[ct][0] = cvtpk(p[0], p[1]);   // k-pair (16ct+4g+0, +1)
      w[ct][1] = cvtpk(p[2], p[3]);   // k-pair (16ct+4g+2, +3)
    }
    // PV cluster: in-register P redistribution + MFMA
    __builtin_amdgcn_s_setprio(1);
#pragma unroll
    for (int kk2 = 0; kk2 < 2; ++kk2) {
      unsigned x0 = w[2 * kk2][0], y0 = w[2 * kk2 + 1][0];
      unsigned x1 = w[2 * kk2][1], y1 = w[2 * kk2 + 1][1];
      asm("v_permlane32_swap_b32 %0, %1" : "+v"(x0), "+v"(y0));
      asm("v_permlane16_swap_b32 %0, %1" : "+v"(x0), "+v"(y0));
      asm("v_permlane32_swap_b32 %0, %1" : "+v"(x1), "+v"(y1));
      asm("v_permlane16_swap_b32 %0, %1" : "+v"(x1), "+v"(y1));
      union { unsigned u[4]; short8 v8; } pau;
      pau.u[0] = x0; pau.u[1] = x1; pau.u[2] = y0; pau.u[3] = y1;
      short8 pa = pau.v8;
#pragma unroll
      for (int ct2 = 0; ct2 < 4; ++ct2) {
        int vrow = ct2 * 16 + r;
        short8 vf = *(const short8*)(bcur + 8192 +
                                     ((vrow * 128 + kk2 * 64 + g * 16) ^ ((vrow & 7) << 4)));
        oacc[ct2] = MFMA16(pa, vf, oacc[ct2]);
      }
    }
    __builtin_amdgcn_s_setprio(0);
    BAR_RAW;
    cur ^= 1;
  }
#pragma unroll
  for (int ct2 = 0; ct2 < 4; ++ct2)
#pragma unroll
    for (int i = 0; i < 4; ++i)
      O[(size_t)(qrow0 + 4 * g + i) * 1024 + h * 64 + ct2 * 16 + r] = f2bf(oacc[ct2][i]);
#undef P1_ISSUE
#undef P2_ISSUE
}

// ---------------------------------------------------------------------------
extern "C" void kernel_launch(void* const* d_in, const int* in_sizes, int n_in,
                              void* d_out, int out_size, void* d_ws, size_t ws_size,
                              hipStream_t stream) {
  const float* q_in = (const float*)d_in[0];
  const float* k_in = (const float*)d_in[1];
  const float* v_in = (const float*)d_in[2];
  const float* wq = (const float*)d_in[3];
  const float* bq = (const float*)d_in[4];
  const float* wk = (const float*)d_in[5];
  const float* bk = (const float*)d_in[6];
  const float* wv = (const float*)d_in[7];
  const float* bv = (const float*)d_in[8];
  const float* wo = (const float*)d_in[9];
  const float* bo = (const float*)d_in[10];

  char* ws = (char*)d_ws;
  const size_t MB8 = 8ull * 1024 * 1024;
  unsigned short* W16 = (unsigned short*)(ws);
  unsigned short* Q16 = (unsigned short*)(ws + MB8);
  unsigned short* K16 = (unsigned short*)(ws + 2 * MB8);
  unsigned short* V16 = (unsigned short*)(ws + 3 * MB8);
  unsigned short* Vt  = (unsigned short*)(ws + 4 * MB8);
  unsigned short* O16 = (unsigned short*)(ws + 3 * MB8);  // alias V16 (dead after transpose)

  float* out = (float*)d_out;
  float* attn = out + 4194304ull;

  dim3 blk(256);
  cast_weights<<<dim3(2048), blk, 0, stream>>>(wq, wk, wv, wo, W16);
  qkv_proj<<<dim3(8, 32, 3), blk, 0, stream>>>(q_in, k_in, v_in, W16, bq, bk, bv, Q16, K16, V16);
  transpose_v<<<dim3(2048), blk, 0, stream>>>(V16, Vt);
  attn_fused<<<dim3(1024), blk, 0, stream>>>(Q16, K16, Vt, attn, O16);
  o_proj<<<dim3(16, 32), blk, 0, stream>>>(O16, W16 + 3145728, bo, out);
}

// Round 14
// 269.311 us; speedup vs baseline: 1.2202x; 1.0779x over previous
//
#include <hip/hip_runtime.h>
#include <stdint.h>

typedef __attribute__((ext_vector_type(4))) float f32x4;
typedef __attribute__((ext_vector_type(8))) short short8;

#define MFMA16(a, b, c) __builtin_amdgcn_mfma_f32_16x16x32_bf16((a), (b), (c), 0, 0, 0)
#define EXP2(x) __builtin_amdgcn_exp2f(x)   // v_exp_f32: 2^x native
#define LOG2(x) __builtin_amdgcn_logf(x)    // v_log_f32: log2 native

__device__ __forceinline__ unsigned short f2bf(float f) {
  unsigned int x = __float_as_uint(f);
  return (unsigned short)((x + 0x7fffu + ((x >> 16) & 1u)) >> 16);
}

__device__ __forceinline__ unsigned int cvtpk(float lo, float hi) {
  unsigned int d;
  asm("v_cvt_pk_bf16_f32 %0, %1, %2" : "=v"(d) : "v"(lo), "v"(hi));
  return d;
}

__device__ __forceinline__ void gl2lds16(const void* g, void* l) {
  __builtin_amdgcn_global_load_lds((const __attribute__((address_space(1))) void*)g,
                                   (__attribute__((address_space(3))) void*)l, 16, 0, 0);
}

__device__ __forceinline__ void load8cv(const float* __restrict__ s, void* d) {
  const f32x4* p = (const f32x4*)s;
  f32x4 a = p[0], b = p[1];
  short8 t;
  t[0] = (short)f2bf(a[0]); t[1] = (short)f2bf(a[1]);
  t[2] = (short)f2bf(a[2]); t[3] = (short)f2bf(a[3]);
  t[4] = (short)f2bf(b[0]); t[5] = (short)f2bf(b[1]);
  t[6] = (short)f2bf(b[2]); t[7] = (short)f2bf(b[3]);
  *(short8*)d = t;
}

// single-barrier pipeline entries: [waitcnt own stage][barrier] -- crossing
// proves (a) all waves' stage-t landed, (b) all waves finished tile t-1.
#define ENT_V0 asm volatile("s_waitcnt vmcnt(0)\ns_barrier" ::: "memory")
#define ENT_V4 asm volatile("s_waitcnt vmcnt(4)\ns_barrier" ::: "memory")

// ---------------------------------------------------------------------------
// cast weights (4x1M) AND inputs (3x4M) f32 -> bf16 in one pass.
// ---------------------------------------------------------------------------
__global__ __launch_bounds__(256) void cast_all(const float* __restrict__ wq,
                                                const float* __restrict__ wk,
                                                const float* __restrict__ wv,
                                                const float* __restrict__ wo,
                                                const float* __restrict__ q_in,
                                                const float* __restrict__ k_in,
                                                const float* __restrict__ v_in,
                                                unsigned short* __restrict__ W16,
                                                unsigned short* __restrict__ Qin,
                                                unsigned short* __restrict__ Kin,
                                                unsigned short* __restrict__ Vin) {
  int i = blockIdx.x * 256 + threadIdx.x;  // 0..2097151, 8 elems each
  if (i < 524288) {
    int which = i >> 17;
    int off = (i & 131071) * 8;
    const float* src = which == 0 ? wq : which == 1 ? wk : which == 2 ? wv : wo;
    load8cv(src + off, W16 + (size_t)which * 1048576 + off);
  } else {
    int j = i - 524288;
    int which = j >> 19;
    int off = (j & 524287) * 8;
    const float* src = which == 0 ? q_in : which == 1 ? k_in : v_in;
    unsigned short* dst = which == 0 ? Qin : which == 1 ? Kin : Vin;
    load8cv(src + off, dst + off);
  }
}

// ---------------------------------------------------------------------------
// Pure-bf16 QKV projection, 128x128 tile, BK=64, both operands via gl2lds.
// Q output (z==0) pre-scaled by 0.125*log2(e): scores land in log2 domain.
// ---------------------------------------------------------------------------
__global__ __launch_bounds__(256) void qkv_proj(const unsigned short* __restrict__ Qin,
                                                const unsigned short* __restrict__ Kin,
                                                const unsigned short* __restrict__ Vin,
                                                const unsigned short* __restrict__ W16,
                                                const float* __restrict__ bq,
                                                const float* __restrict__ bk,
                                                const float* __restrict__ bv,
                                                unsigned short* __restrict__ Q16,
                                                unsigned short* __restrict__ K16,
                                                unsigned short* __restrict__ V16) {
  const int z = blockIdx.z;
  const unsigned short* A = z == 0 ? Qin : z == 1 ? Kin : Vin;
  const unsigned short* Bt = W16 + (size_t)z * 1048576;
  const float* bias = z == 0 ? bq : z == 1 ? bk : bv;
  unsigned short* C = z == 0 ? Q16 : z == 1 ? K16 : V16;
  const float oscale = z == 0 ? 0.18033688f : 1.0f;  // 0.125 * log2(e)
  const int K = 1024, N = 1024;

  __shared__ __align__(16) char lds[32768];  // As 16KB | Bs 16KB
  char* As = lds;
  char* Bs = lds + 16384;
  const int tid = threadIdx.x;
  const int lane = tid & 63;
  const int wv = tid >> 6;
  const int g = lane >> 4, r = lane & 15;
  const int wm = wv >> 1, wn = wv & 1;
  const int m0 = blockIdx.y * 128, n0 = blockIdx.x * 128;

  f32x4 acc[4][4];
#pragma unroll
  for (int m = 0; m < 4; ++m)
#pragma unroll
    for (int n = 0; n < 4; ++n) acc[m][n] = (f32x4){0.f, 0.f, 0.f, 0.f};

  for (int k0 = 0; k0 < K; k0 += 64) {
    __syncthreads();
#pragma unroll
    for (int i = 0; i < 4; ++i) {
      int c = (wv * 4 + i) * 64 + lane;
      int row = c >> 3;
      gl2lds16(Bt + (size_t)(n0 + row) * K + k0 + (c & 7) * 8, Bs + (wv * 4 + i) * 1024);
    }
#pragma unroll
    for (int i = 0; i < 4; ++i) {
      int c = (wv * 4 + i) * 64 + lane;
      int row = c >> 3;
      gl2lds16(A + (size_t)(m0 + row) * K + k0 + (c & 7) * 8, As + (wv * 4 + i) * 1024);
    }
    __syncthreads();
#pragma unroll
    for (int kk = 0; kk < 2; ++kk) {
      short8 af[4], bfr[4];
#pragma unroll
      for (int m = 0; m < 4; ++m)
        af[m] = *(const short8*)(As + (wm * 64 + m * 16 + r) * 128 + kk * 64 + g * 16);
#pragma unroll
      for (int n = 0; n < 4; ++n)
        bfr[n] = *(const short8*)(Bs + (wn * 64 + n * 16 + r) * 128 + kk * 64 + g * 16);
#pragma unroll
      for (int m = 0; m < 4; ++m)
#pragma unroll
        for (int n = 0; n < 4; ++n) acc[m][n] = MFMA16(af[m], bfr[n], acc[m][n]);
    }
  }

#pragma unroll
  for (int n = 0; n < 4; ++n) {
    int col = n0 + wn * 64 + n * 16 + r;
    float bv_ = bias[col];
#pragma unroll
    for (int m = 0; m < 4; ++m)
#pragma unroll
      for (int i = 0; i < 4; ++i) {
        int rowg = m0 + wm * 64 + m * 16 + 4 * g + i;
        C[(size_t)rowg * N + col] = f2bf((acc[m][n][i] + bv_) * oscale);
      }
  }
}

// ---------------------------------------------------------------------------
__global__ __launch_bounds__(256) void o_proj(const unsigned short* __restrict__ A,
                                              const unsigned short* __restrict__ Bt,
                                              const float* __restrict__ bias,
                                              float* __restrict__ C) {
  const int K = 1024, N = 1024;
  __shared__ __align__(16) char lds[24576];
  char* As = lds;
  char* Bs = lds + 16384;
  const int tid = threadIdx.x;
  const int lane = tid & 63;
  const int wv = tid >> 6;
  const int g = lane >> 4, r = lane & 15;
  const int wm = wv >> 1, wn = wv & 1;
  const int m0 = blockIdx.y * 128, n0 = blockIdx.x * 64;

  f32x4 acc[4][2];
#pragma unroll
  for (int m = 0; m < 4; ++m)
#pragma unroll
    for (int n = 0; n < 2; ++n) acc[m][n] = (f32x4){0.f, 0.f, 0.f, 0.f};

  for (int k0 = 0; k0 < K; k0 += 64) {
    __syncthreads();
#pragma unroll
    for (int i = 0; i < 2; ++i) {
      int c = (wv * 2 + i) * 64 + lane;
      int row = c >> 3;
      gl2lds16(Bt + (size_t)(n0 + row) * K + k0 + (c & 7) * 8, Bs + (wv * 2 + i) * 1024);
    }
#pragma unroll
    for (int i = 0; i < 4; ++i) {
      int c = (wv * 4 + i) * 64 + lane;
      int row = c >> 3;
      gl2lds16(A + (size_t)(m0 + row) * K + k0 + (c & 7) * 8, As + (wv * 4 + i) * 1024);
    }
    __syncthreads();
#pragma unroll
    for (int kk = 0; kk < 2; ++kk) {
      short8 af[4], bfr[2];
#pragma unroll
      for (int m = 0; m < 4; ++m)
        af[m] = *(const short8*)(As + (wm * 64 + m * 16 + r) * 128 + kk * 64 + g * 16);
#pragma unroll
      for (int n = 0; n < 2; ++n)
        bfr[n] = *(const short8*)(Bs + (wn * 32 + n * 16 + r) * 128 + kk * 64 + g * 16);
#pragma unroll
      for (int m = 0; m < 4; ++m)
#pragma unroll
        for (int n = 0; n < 2; ++n) acc[m][n] = MFMA16(af[m], bfr[n], acc[m][n]);
    }
  }

#pragma unroll
  for (int n = 0; n < 2; ++n) {
    int col = n0 + wn * 32 + n * 16 + r;
    float bv_ = bias[col];
#pragma unroll
    for (int m = 0; m < 4; ++m)
#pragma unroll
      for (int i = 0; i < 4; ++i) {
        int rowg = m0 + wm * 64 + m * 16 + 4 * g + i;
        C[(size_t)rowg * N + col] = acc[m][n][i] + bv_;
      }
  }
}

// ---------------------------------------------------------------------------
__global__ __launch_bounds__(256) void transpose_v(const unsigned short* __restrict__ V,
                                                   unsigned short* __restrict__ Vt) {
  int t = blockIdx.x * 256 + threadIdx.x;
  int d = t & 63;
  int sc = (t >> 6) & 255;
  int bh = t >> 14;
  int b = bh >> 4, h = bh & 15;
  unsigned short vals[8];
#pragma unroll
  for (int j = 0; j < 8; ++j)
    vals[j] = V[(size_t)(b * 2048 + sc * 8 + j) * 1024 + h * 64 + d];
  *(short8*)&Vt[((size_t)bh * 64 + d) * 2048 + sc * 8] = *(short8*)vals;
}

// ---------------------------------------------------------------------------
// Fused attention v14 = v13 + single-barrier pipeline:
// per tile: [waitcnt own stage-t][s_barrier][issue stage t+1][compute t].
// Crossing the barrier proves all waves' stage-t landed AND all finished
// t-1, so overwriting buffer t-1 after it is race-free. 1 barrier/tile.
// ---------------------------------------------------------------------------
__global__ __launch_bounds__(256, 4) void attn_fused(const unsigned short* __restrict__ Q,
                                                     const unsigned short* __restrict__ K,
                                                     const unsigned short* __restrict__ Vt,
                                                     float* __restrict__ attn,
                                                     unsigned short* __restrict__ O) {
  __shared__ __align__(16) char lds[32768];  // K/V double buffer only
  const int tid = threadIdx.x;
  const int lane = tid & 63;
  const int wv = tid >> 6;
  const int g = lane >> 4, r = lane & 15;
  int nb = (blockIdx.x & 7) * 128 + (blockIdx.x >> 3);
  const int qt = nb & 31, bh = nb >> 5, h = bh & 15, b = bh >> 4;
  const int qloc = qt * 64 + wv * 16;
  const int qrow0 = b * 2048 + qloc;
  const unsigned short* Kbh = K + (size_t)b * 2048 * 1024 + h * 64;
  const unsigned short* Vbh = Vt + (size_t)bh * 64 * 2048;
  float* attn_bh = attn + (size_t)bh * 2048 * 2048;

  short8 qf[2];
#pragma unroll
  for (int kk = 0; kk < 2; ++kk)
    qf[kk] = *(const short8*)&Q[(size_t)(qrow0 + r) * 1024 + h * 64 + kk * 32 + g * 8];

#define P1_ISSUE(bb, ktt)                                                      \
  do {                                                                         \
    _Pragma("unroll") for (int i_ = 0; i_ < 4; ++i_) {                         \
      int c_ = (wv * 4 + i_) * 64 + lane;                                      \
      int kr_ = c_ >> 3;                                                       \
      int scb_ = ((c_ & 7) * 16) ^ ((kr_ & 7) << 4);                           \
      gl2lds16(Kbh + (size_t)((ktt) + kr_) * 1024 + (scb_ >> 1),               \
               (bb) + (wv * 4 + i_) * 1024);                                   \
    }                                                                          \
  } while (0)
#define P2_ISSUE(bb, ktt)                                                      \
  do {                                                                         \
    _Pragma("unroll") for (int i_ = 0; i_ < 4; ++i_) {                         \
      int c_ = (wv * 4 + i_) * 64 + lane;                                      \
      int kr_ = (c_ >> 3) & 63;                                                \
      int scb_ = ((c_ & 7) * 16) ^ ((kr_ & 7) << 4);                           \
      const unsigned short* src_ =                                             \
          (c_ < 512) ? (Kbh + (size_t)((ktt) + kr_) * 1024 + (scb_ >> 1))      \
                     : (Vbh + (size_t)kr_ * 2048 + (ktt) + (scb_ >> 1));       \
      gl2lds16(src_, (bb) + (wv * 4 + i_) * 1024);                             \
    }                                                                          \
  } while (0)

  // ---------------- pass 1: per-lane exp2-sum, KVBLK=128, 1 barrier/tile ----
  float lrow = 0.f;
  int cur = 0;
  P1_ISSUE(lds, 0);
  for (int t = 0; t < 16; ++t) {
    char* bcur = lds + (cur << 14);
    ENT_V0;  // my stage-t landed; everyone past compute(t-1)
    if (t < 15) P1_ISSUE(lds + ((cur ^ 1) << 14), (t + 1) * 128);
#pragma unroll
    for (int ct = 0; ct < 8; ++ct) {
      int row = ct * 16 + r;
      int sw = (row & 7) << 4;
      short8 kf0 = *(const short8*)(bcur + ((row * 128 + g * 16) ^ sw));
      short8 kf1 = *(const short8*)(bcur + ((row * 128 + 64 + g * 16) ^ sw));
      f32x4 s = (f32x4){0.f, 0.f, 0.f, 0.f};
      s = MFMA16(kf0, qf[0], s);
      s = MFMA16(kf1, qf[1], s);
      lrow += (EXP2(s[0]) + EXP2(s[1])) + (EXP2(s[2]) + EXP2(s[3]));
    }
    cur ^= 1;
  }
  lrow += __shfl_xor(lrow, 16);
  lrow += __shfl_xor(lrow, 32);
  const float negml = -LOG2(lrow);
  const f32x4 cinit = (f32x4){negml, negml, negml, negml};

  // ---------------- pass 2: nt-store + permlane P + PV, 1 barrier/tile ------
  f32x4 oacc[4];
#pragma unroll
  for (int i = 0; i < 4; ++i) oacc[i] = (f32x4){0.f, 0.f, 0.f, 0.f};

  float* arow = attn_bh + (size_t)(qloc + r) * 2048 + 4 * g;
  cur = 0;
  P2_ISSUE(lds, 0);
  for (int t = 0; t < 32; ++t) {
    char* bcur = lds + (cur << 14);
    int kt = t * 64;
    if (t == 0) {
      ENT_V0;  // only initial stage outstanding
    } else {
      ENT_V4;  // retire stage(t):4 oldest; stores(t-1):4 keep flowing
    }
    if (t < 31) P2_ISSUE(lds + ((cur ^ 1) << 14), kt + 64);
    // QK^T (C-init = -log2 l) -> p = exp2(s) already normalized
    unsigned w[4][2];
#pragma unroll
    for (int ct = 0; ct < 4; ++ct) {
      int row = ct * 16 + r;
      int sw = (row & 7) << 4;
      short8 kf0 = *(const short8*)(bcur + ((row * 128 + g * 16) ^ sw));
      short8 kf1 = *(const short8*)(bcur + ((row * 128 + 64 + g * 16) ^ sw));
      f32x4 s = MFMA16(kf0, qf[0], cinit);
      s = MFMA16(kf1, qf[1], s);
      f32x4 p;
      p[0] = EXP2(s[0]); p[1] = EXP2(s[1]);
      p[2] = EXP2(s[2]); p[3] = EXP2(s[3]);
      __builtin_nontemporal_store(p, (f32x4*)(arow + kt + 16 * ct));
      w[ct][0] = cvtpk(p[0], p[1]);
      w[ct][1] = cvtpk(p[2], p[3]);
    }
    // PV cluster: in-register P redistribution + MFMA
    __builtin_amdgcn_s_setprio(1);
#pragma unroll
    for (int kk2 = 0; kk2 < 2; ++kk2) {
      unsigned x0 = w[2 * kk2][0], y0 = w[2 * kk2 + 1][0];
      unsigned x1 = w[2 * kk2][1], y1 = w[2 * kk2 + 1][1];
      asm("v_permlane32_swap_b32 %0, %1" : "+v"(x0), "+v"(y0));
      asm("v_permlane16_swap_b32 %0, %1" : "+v"(x0), "+v"(y0));
      asm("v_permlane32_swap_b32 %0, %1" : "+v"(x1), "+v"(y1));
      asm("v_permlane16_swap_b32 %0, %1" : "+v"(x1), "+v"(y1));
      union { unsigned u[4]; short8 v8; } pau;
      pau.u[0] = x0; pau.u[1] = x1; pau.u[2] = y0; pau.u[3] = y1;
      short8 pa = pau.v8;
#pragma unroll
      for (int ct2 = 0; ct2 < 4; ++ct2) {
        int vrow = ct2 * 16 + r;
        short8 vf = *(const short8*)(bcur + 8192 +
                                     ((vrow * 128 + kk2 * 64 + g * 16) ^ ((vrow & 7) << 4)));
        oacc[ct2] = MFMA16(pa, vf, oacc[ct2]);
      }
    }
    __builtin_amdgcn_s_setprio(0);
    cur ^= 1;
  }
#pragma unroll
  for (int ct2 = 0; ct2 < 4; ++ct2)
#pragma unroll
    for (int i = 0; i < 4; ++i)
      O[(size_t)(qrow0 + 4 * g + i) * 1024 + h * 64 + ct2 * 16 + r] = f2bf(oacc[ct2][i]);
#undef P1_ISSUE
#undef P2_ISSUE
}

// ---------------------------------------------------------------------------
extern "C" void kernel_launch(void* const* d_in, const int* in_sizes, int n_in,
                              void* d_out, int out_size, void* d_ws, size_t ws_size,
                              hipStream_t stream) {
  const float* q_in = (const float*)d_in[0];
  const float* k_in = (const float*)d_in[1];
  const float* v_in = (const float*)d_in[2];
  const float* wq = (const float*)d_in[3];
  const float* bq = (const float*)d_in[4];
  const float* wk = (const float*)d_in[5];
  const float* bk = (const float*)d_in[6];
  const float* wv = (const float*)d_in[7];
  const float* bv = (const float*)d_in[8];
  const float* wo = (const float*)d_in[9];
  const float* bo = (const float*)d_in[10];

  char* ws = (char*)d_ws;
  const size_t MB8 = 8ull * 1024 * 1024;
  unsigned short* W16 = (unsigned short*)(ws);
  unsigned short* Qin = (unsigned short*)(ws + MB8);
  unsigned short* Kin = (unsigned short*)(ws + 2 * MB8);
  unsigned short* Vin = (unsigned short*)(ws + 3 * MB8);
  unsigned short* Q16 = (unsigned short*)(ws + 4 * MB8);
  unsigned short* K16 = (unsigned short*)(ws + 5 * MB8);
  unsigned short* V16 = (unsigned short*)(ws + 6 * MB8);
  unsigned short* Vt  = (unsigned short*)(ws + 7 * MB8);
  unsigned short* O16 = (unsigned short*)(ws + 6 * MB8);  // alias V16 (dead after transpose)

  float* out = (float*)d_out;
  float* attn = out + 4194304ull;

  dim3 blk(256);
  cast_all<<<dim3(8192), blk, 0, stream>>>(wq, wk, wv, wo, q_in, k_in, v_in, W16, Qin, Kin, Vin);
  qkv_proj<<<dim3(8, 32, 3), blk, 0, stream>>>(Qin, Kin, Vin, W16, bq, bk, bv, Q16, K16, V16);
  transpose_v<<<dim3(2048), blk, 0, stream>>>(V16, Vt);
  attn_fused<<<dim3(1024), blk, 0, stream>>>(Q16, K16, Vt, attn, O16);
  o_proj<<<dim3(16, 32), blk, 0, stream>>>(O16, W16 + 3145728, bo, out);
}